// Round 6
// baseline (1599.604 us; speedup 1.0000x reference)
//
#include <hip/hip_runtime.h>
#include <hip/hip_cooperative_groups.h>

namespace cg = cooperative_groups;

// ---------- helpers ----------
__device__ __forceinline__ float bf2f(unsigned short u) {
  union { unsigned int i; float f; } v; v.i = ((unsigned int)u) << 16; return v.f;
}
__device__ __forceinline__ unsigned short f2bf(float f) {
  union { float f; unsigned int i; } v; v.f = f;
  unsigned int x = v.i;
  return (unsigned short)((x + 0x7fffu + ((x >> 16) & 1u)) >> 16);
}
__device__ __forceinline__ float sigmf(float x) { return 1.f / (1.f + __expf(-x)); }

typedef float f32x4 __attribute__((ext_vector_type(4)));
typedef short short8v __attribute__((ext_vector_type(8)));
typedef short short4v __attribute__((ext_vector_type(4)));

// pack 8 f32 -> 8 bf16 (truncate)
__device__ __forceinline__ short8v pack8(const float* p) {
  union { short8v s; unsigned int u[4]; } r;
#pragma unroll
  for (int i = 0; i < 4; ++i) {
    unsigned int lo = __float_as_uint(p[2 * i]) >> 16;
    unsigned int hi = __float_as_uint(p[2 * i + 1]) & 0xFFFF0000u;
    r.u[i] = hi | lo;
  }
  return r.s;
}

// ---------- sizes ----------
// conv1: (128,1,257,128) -> conv 253x124 -> pool3 -> (128,64,84,41)
// conv2: -> conv 85x42 -> pool3 -> (128,5,28,14) -> feat (128,1960) [bf16, KP=1984]

#define KP 1984
#define NP 5888

// ---------- prep: conv1 weight fragments (uniform K=128 map) ----------
// k = fr*12 + fc (fc padded to 12); k>=108 -> 0; fc>=9 -> 0.
// w1f[((ocf*4+s)*64+l)*8+j] = W[oc=ocf*16+(l&15)][k=32s+(l>>4)*8+j]
__global__ void k_w1frag(const float* __restrict__ w1, unsigned short* __restrict__ w1f) {
  int idx = blockIdx.x * 256 + threadIdx.x;
  if (idx >= 4 * 4 * 64 * 8) return;
  int j = idx & 7, l = (idx >> 3) & 63;
  int rest = idx >> 9;  // 0..15
  int s = rest & 3, ocf = rest >> 2;
  int oc = ocf * 16 + (l & 15);
  int k = s * 32 + (l >> 4) * 8 + j;
  float v = 0.f;
  if (k < 108) {
    int fr = k / 12, fc = k - fr * 12;
    if (fc < 9) v = w1[oc * 81 + fr * 9 + fc];
  }
  w1f[idx] = f2bf(v);
}

// ---------- prep: conv2 weight fragments ----------
__global__ void k_w2frag(const float* __restrict__ w2, unsigned short* __restrict__ w2f) {
  int idx = blockIdx.x * 256 + threadIdx.x;
  if (idx >= 32 * 64 * 8) return;
  int j = idx & 7, l = (idx >> 3) & 63, s = idx >> 9;
  int oc = l & 15;
  int k = s * 32 + (l >> 4) * 8 + j;
  int t = k >> 6, ch = k & 63, fr = t >> 2, fc = t & 3;
  float v = (oc < 5) ? w2[((oc * 64 + ch) * 4 + fr) * 4 + fc] : 0.f;
  w2f[idx] = f2bf(v);
}

// ---------- prep: w_ih f32 [5880][1960] -> bf16 [5888][1984] zero-padded ----------
__global__ void k_cvt_wih(const float* __restrict__ src, unsigned short* __restrict__ dst) {
  const int total = NP * KP / 8;
  int idx = blockIdx.x * 256 + threadIdx.x;
  if (idx >= total) return;
  int row = idx / (KP / 8);
  int c8 = (idx - row * (KP / 8)) * 8;
  short8v v = {0, 0, 0, 0, 0, 0, 0, 0};
  if (row < 5880 && c8 < 1960) {
    const float* s = src + (size_t)row * 1960 + c8;
    if (c8 + 8 <= 1960) {
      float tmp[8];
#pragma unroll
      for (int i = 0; i < 8; ++i) tmp[i] = s[i];
      v = pack8(tmp);
    } else {
      union { short8v s8; unsigned short us[8]; } u; u.s8 = v;
      for (int i = 0; i < 1960 - c8; ++i) u.us[i] = f2bf(s[i]);
      v = u.s8;
    }
  }
  *reinterpret_cast<short8v*>(dst + (size_t)idx * 8) = v;
}

// ---------- prep: zero feat_bf K-pad columns ----------
__global__ void k_featpad(unsigned short* __restrict__ feat_bf) {
  for (int i = threadIdx.x; i < 128 * 24; i += 256) {
    int n = i / 24, k = 1960 + i % 24;
    feat_bf[(size_t)n * KP + k] = 0;
  }
}

// ---------- kernel 1: conv1 MFMA, uniform K=128, 4-shift-copy LDS ----------
// s_b[4][22][140] bf16; copy m slot d holds input col (d-m)-2 of staged row.
// Fragment (s,g): k0=32s+8g, fr0=k0/12, fc0=k0%12:
//   fc0 in {0,4}: 8-run row fr0 cols cc..cc+7 (cc=c+fc0) -> RA, RA+4
//   fc0 == 8   : 4-run row fr0 cols c+8..c+11 + 4-run row fr0+1 cols c..c+3
__global__ __launch_bounds__(256) void k_conv1(const float* __restrict__ x,
                                               const unsigned short* __restrict__ w1f,
                                               const float* __restrict__ b1,
                                               unsigned short* __restrict__ pool1) {
  const int n = blockIdx.x, qrg = blockIdx.y;
  const int b = n >> 5, w = n & 31;
  __shared__ __align__(16) unsigned short s_b[4 * 22 * 140];
  const int tid = threadIdx.x;
  // stage rows lr 0..21 (f = 12qrg+lr-2; lr>=20 zero), source cols lc 0..143 (t=lc-2)
  for (int i = tid; i < 22 * 144; i += 256) {
    int lr = i / 144, lc = i - lr * 144;
    int f = 12 * qrg + lr - 2;
    int t = lc - 2;
    float v = 0.f;
    if (lr < 20 && f >= 0 && f < 257 && t >= 0 && t < 128)
      v = x[((size_t)b * 258 + 1 + f) * 2176 + w * 64 + t];
    unsigned short bf = f2bf(v);
#pragma unroll
    for (int m = 0; m < 4; ++m) {
      int d = lc + m;
      if (d < 140) s_b[m * 3080 + lr * 140 + d] = bf;
    }
  }
  const int lane = tid & 63, wv = tid >> 6;
  // weight fragments
  short8v bw[4][4];
#pragma unroll
  for (int ocf = 0; ocf < 4; ++ocf)
#pragma unroll
    for (int s = 0; s < 4; ++s)
      bw[ocf][s] = *reinterpret_cast<const short8v*>(&w1f[((ocf * 4 + s) * 64 + lane) * 8]);
  __syncthreads();

  const int li = lane & 15, g = lane >> 4;
  // per-lane step constants
  int fr0s[4], fc0s[4], is8s[4];
#pragma unroll
  for (int s = 0; s < 4; ++s) {
    int k0 = 32 * s + 8 * g;
    int fr = k0 / 12;
    int fc = k0 - fr * 12;
    fr0s[s] = fr; fc0s[s] = fc; is8s[s] = (fc == 8);
  }
  // bias per (ocf, li)
  float bv[4];
#pragma unroll
  for (int ocf = 0; ocf < 4; ++ocf) bv[ocf] = b1[ocf * 16 + li];

  const int qr = qrg * 4 + wv;  // pool row

  for (int pgt = 0; pgt < 3; ++pgt) {
    int pg = pgt * 16 + li;
    if (pg > 40) pg = 40;
    const int c0 = 3 * pg;
    // precompute addresses (u16 indices)
    int RA[3][4], RB[3][4];
#pragma unroll
    for (int phi = 0; phi < 3; ++phi) {
#pragma unroll
      for (int s = 0; s < 4; ++s) {
        int cc = c0 + phi + fc0s[s];
        int m = (-cc) & 3;
        RA[phi][s] = m * 3080 + fr0s[s] * 140 + cc + m;
        int cc2 = c0 + phi;
        int m2 = (-cc2) & 3;
        int rb8 = m2 * 3080 + (fr0s[s] + 1) * 140 + cc2 + m2;
        RB[phi][s] = is8s[s] ? rb8 : (RA[phi][s] + 4);
      }
    }
    f32x4 pm[4];
#pragma unroll
    for (int ocf = 0; ocf < 4; ++ocf) pm[ocf] = (f32x4){-3.4e38f, -3.4e38f, -3.4e38f, -3.4e38f};

    for (int rr = 0; rr < 3; ++rr) {
      const int ro = (3 * wv + rr) * 140;
#pragma unroll
      for (int phi = 0; phi < 3; ++phi) {
        f32x4 acc[4];
#pragma unroll
        for (int ocf = 0; ocf < 4; ++ocf) acc[ocf] = (f32x4){0.f, 0.f, 0.f, 0.f};
#pragma unroll
        for (int s = 0; s < 4; ++s) {
          short4v lo = *reinterpret_cast<const short4v*>(&s_b[ro + RA[phi][s]]);
          short4v hi = *reinterpret_cast<const short4v*>(&s_b[ro + RB[phi][s]]);
          short8v a = __builtin_shufflevector(lo, hi, 0, 1, 2, 3, 4, 5, 6, 7);
#pragma unroll
          for (int ocf = 0; ocf < 4; ++ocf)
            acc[ocf] = __builtin_amdgcn_mfma_f32_16x16x32_bf16(a, bw[ocf][s], acc[ocf], 0, 0, 0);
        }
#pragma unroll
        for (int ocf = 0; ocf < 4; ++ocf) {
#pragma unroll
          for (int i = 0; i < 4; ++i) pm[ocf][i] = fmaxf(pm[ocf][i], acc[ocf][i]);
        }
      }
    }
    // store: D row = g*4+i = pool col, D col = li -> oc = ocf*16+li
#pragma unroll
    for (int ocf = 0; ocf < 4; ++ocf) {
#pragma unroll
      for (int i = 0; i < 4; ++i) {
        int pg2 = pgt * 16 + g * 4 + i;
        if (pg2 <= 40) {
          int oc = ocf * 16 + li;
          pool1[(((size_t)n * 84 + qr) * 41 + pg2) * 64 + oc] = f2bf(sigmf(pm[ocf][i] + bv[ocf]));
        }
      }
    }
  }
}

// ---------- kernel 2: conv2 MFMA, LDS-staged A, weights in regs ----------
__global__ __launch_bounds__(128, 2) void k_conv2(const unsigned short* __restrict__ pool1,
                                                  const unsigned short* __restrict__ w2f,
                                                  const float* __restrict__ b2,
                                                  unsigned short* __restrict__ feat_bf) {
  const int n = blockIdx.x, qg = blockIdx.y;  // qg 0..13
  __shared__ __align__(16) unsigned short s_a[9 * 46 * 64];
  const int tid = threadIdx.x;
  const int lane = tid & 63, wv = tid >> 6;
  short8v bwr[32];
#pragma unroll
  for (int s = 0; s < 32; ++s)
    bwr[s] = *reinterpret_cast<const short8v*>(&w2f[(s * 64 + lane) * 8]);
  const int r0 = 6 * qg - 2;
  for (int idx = tid; idx < 9 * 46 * 8; idx += 128) {
    int row = idx / (46 * 8);
    int rem = idx - row * (46 * 8);
    int lc = rem >> 3, cp = rem & 7;
    int gr = r0 + row, gc = lc - 2;
    short8v v = {0, 0, 0, 0, 0, 0, 0, 0};
    if ((unsigned)gr < 84u && (unsigned)gc < 41u)
      v = *reinterpret_cast<const short8v*>(&pool1[(((size_t)n * 84 + gr) * 41 + gc) * 64 + cp * 8]);
    int rot = (cp * 8 + lc * 8) & 63;
    *reinterpret_cast<short8v*>(&s_a[(row * 46 + lc) * 64 + rot]) = v;
  }
  __syncthreads();

  const int q = qg * 2 + wv;
  const int li = lane & 15, g = lane >> 4;
  const int pg = li > 13 ? 13 : li;
  f32x4 pm = (f32x4){-3.4e38f, -3.4e38f, -3.4e38f, -3.4e38f};

  for (int rr = 0; rr < 3; ++rr) {
#pragma unroll
    for (int phi = 0; phi < 3; ++phi) {
      f32x4 acc[4];
#pragma unroll
      for (int i = 0; i < 4; ++i) acc[i] = (f32x4){0.f, 0.f, 0.f, 0.f};
#pragma unroll
      for (int s = 0; s < 32; ++s) {
        const int t = s >> 1, h = s & 1;
        const int fr = t >> 2, fc = t & 3;
        const int srow = 3 * wv + rr + fr;
        const int lc = 3 * pg + phi + fc;
        const int rot = (h * 32 + g * 8 + lc * 8) & 63;
        short8v a = *reinterpret_cast<const short8v*>(&s_a[(srow * 46 + lc) * 64 + rot]);
        acc[s & 3] = __builtin_amdgcn_mfma_f32_16x16x32_bf16(a, bwr[s], acc[s & 3], 0, 0, 0);
      }
      f32x4 sum;
#pragma unroll
      for (int i = 0; i < 4; ++i) sum[i] = (acc[0][i] + acc[1][i]) + (acc[2][i] + acc[3][i]);
#pragma unroll
      for (int i = 0; i < 4; ++i) pm[i] = fmaxf(pm[i], sum[i]);
    }
  }
  if (li < 5) {
#pragma unroll
    for (int i = 0; i < 4; ++i) {
      int pq = g * 4 + i;
      if (pq < 14)
        feat_bf[(size_t)n * KP + li * 392 + q * 14 + pq] = f2bf(sigmf(pm[i] + b2[li]));
    }
  }
}

// ---------- kernel 3: f32 -> bf16 convert (w_hh) ----------
__global__ void k_cvt(const float* __restrict__ src, unsigned short* __restrict__ dst, int n4) {
  for (int i = blockIdx.x * blockDim.x + threadIdx.x; i < n4; i += gridDim.x * blockDim.x) {
    float4 v = *reinterpret_cast<const float4*>(&src[i * 4]);
    ushort4 u;
    u.x = f2bf(v.x); u.y = f2bf(v.y); u.z = f2bf(v.z); u.w = f2bf(v.w);
    *reinterpret_cast<ushort4*>(&dst[i * 4]) = u;
  }
}

// ---------- kernel 4: gi MFMA GEMM ----------
__global__ __launch_bounds__(256) void k_gi(const unsigned short* __restrict__ feat_bf,
                                            const unsigned short* __restrict__ wih_bf,
                                            const float* __restrict__ b_ih,
                                            float* __restrict__ gi) {
  const int bx = blockIdx.x, bm = blockIdx.y;
  const int w = threadIdx.x >> 6, lane = threadIdx.x & 63;
  const int li = lane & 15, g = lane >> 4;
  const unsigned short* ap = feat_bf + (size_t)(bm * 64 + w * 16 + li) * KP + g * 8;
  const unsigned short* bp = wih_bf + (size_t)(bx * 16 + li) * KP + g * 8;
  f32x4 acc0 = (f32x4){0.f, 0.f, 0.f, 0.f};
  f32x4 acc1 = (f32x4){0.f, 0.f, 0.f, 0.f};
  for (int kc = 0; kc < 62; kc += 2) {
    short8v a0 = *reinterpret_cast<const short8v*>(ap + kc * 32);
    short8v b0 = *reinterpret_cast<const short8v*>(bp + kc * 32);
    short8v a1 = *reinterpret_cast<const short8v*>(ap + kc * 32 + 32);
    short8v b1 = *reinterpret_cast<const short8v*>(bp + kc * 32 + 32);
    acc0 = __builtin_amdgcn_mfma_f32_16x16x32_bf16(a0, b0, acc0, 0, 0, 0);
    acc1 = __builtin_amdgcn_mfma_f32_16x16x32_bf16(a1, b1, acc1, 0, 0, 0);
  }
  const int j = bx * 16 + li;
  if (j < 5880) {
    const float bi = b_ih[j];
    const int n0 = bm * 64 + w * 16 + g * 4;
#pragma unroll
    for (int i = 0; i < 4; ++i)
      gi[(size_t)(n0 + i) * 5880 + j] = acc0[i] + acc1[i] + bi;
  }
}

// ---------- kernel 5: all 32 GRU steps, cooperative (grid.sync between steps) ----------
__global__ __launch_bounds__(768) void k_gru(const unsigned short* __restrict__ whh,
                                             const float* __restrict__ b_hh,
                                             const float* __restrict__ gi,
                                             const float* __restrict__ hx0,
                                             float* __restrict__ h0,
                                             float* __restrict__ h1) {
  cg::grid_group grid = cg::this_grid();
  __shared__ float s_h[7840];
  __shared__ float s_p[96 * 8];
  __shared__ float s_gh[96];
  const int k0 = blockIdx.x * 8;
  const int kq = threadIdx.x & 7;
  const int d = threadIdx.x >> 3;  // 0..95
  const int kk = d & 7;
  const int b = (d >> 3) & 3;
  const int g = d >> 5;
  const int j = g * 1960 + k0 + kk;
  const unsigned short* wrow = whh + (size_t)j * 1960;
  const float* hrow = s_h + b * 1960;

  for (int t = 0; t < 32; ++t) {
    const float* hin = (t == 0) ? hx0 : ((t & 1) ? h1 : h0);
    float* hout = (t & 1) ? h0 : h1;
    for (int i = threadIdx.x; i < 1960; i += 768) {
      float4 v = *reinterpret_cast<const float4*>(&hin[4 * i]);
      *reinterpret_cast<float4*>(&s_h[4 * i]) = v;
    }
    __syncthreads();
    float acc = 0.f;
    for (int c = kq; c < 245; c += 8) {
      union { short8v s; unsigned short us[8]; } u;
      u.s = *reinterpret_cast<const short8v*>(&wrow[c * 8]);
      float4 hv0 = *reinterpret_cast<const float4*>(&hrow[c * 8]);
      float4 hv1 = *reinterpret_cast<const float4*>(&hrow[c * 8 + 4]);
      acc += bf2f(u.us[0]) * hv0.x + bf2f(u.us[1]) * hv0.y + bf2f(u.us[2]) * hv0.z + bf2f(u.us[3]) * hv0.w +
             bf2f(u.us[4]) * hv1.x + bf2f(u.us[5]) * hv1.y + bf2f(u.us[6]) * hv1.z + bf2f(u.us[7]) * hv1.w;
    }
    s_p[d * 8 + kq] = acc;
    __syncthreads();
    if (threadIdx.x < 96) {
      const int tt = threadIdx.x;
      float s = 0.f;
#pragma unroll
      for (int q = 0; q < 8; ++q) s += s_p[tt * 8 + q];
      const int tkk = tt & 7, tg = tt >> 5;
      s_gh[tt] = s + b_hh[tg * 1960 + k0 + tkk];
    }
    __syncthreads();
    if (threadIdx.x < 32) {
      const int ck = threadIdx.x & 7, cb = threadIdx.x >> 3;
      const int k = k0 + ck;
      const int nrow = (cb * 32 + t) * 5880;
      const float ghr = s_gh[ck + 8 * cb];
      const float ghz = s_gh[ck + 8 * cb + 32];
      const float ghn = s_gh[ck + 8 * cb + 64];
      const float r = sigmf(gi[nrow + k] + ghr);
      const float z = sigmf(gi[nrow + 1960 + k] + ghz);
      const float nn = tanhf(gi[nrow + 3920 + k] + r * ghn);
      const float hp = s_h[cb * 1960 + k];
      hout[cb * 1960 + k] = (1.f - z) * nn + z * hp;
    }
    grid.sync();
  }
}

// ---------- kernel 6: fc + softmax + labels ----------
__global__ void k_fc(const float* __restrict__ h, const float* __restrict__ fc_w,
                     const float* __restrict__ fc_b, const int* __restrict__ labels,
                     float* __restrict__ out) {
  const int l = threadIdx.x;
  float acc[8];
#pragma unroll
  for (int i = 0; i < 8; ++i) acc[i] = 0.f;
  for (int k = l; k < 1960; k += 64) {
    const float w0 = fc_w[k], w1 = fc_w[1960 + k];
#pragma unroll
    for (int b = 0; b < 4; ++b) {
      const float hv = h[b * 1960 + k];
      acc[b * 2 + 0] += hv * w0;
      acc[b * 2 + 1] += hv * w1;
    }
  }
#pragma unroll
  for (int i = 0; i < 8; ++i) {
    float a = acc[i];
#pragma unroll
    for (int off = 32; off; off >>= 1) a += __shfl_xor(a, off, 64);
    acc[i] = a;
  }
  if (l == 0) {
#pragma unroll
    for (int b = 0; b < 4; ++b) {
      const float l0 = acc[b * 2] + fc_b[0], l1 = acc[b * 2 + 1] + fc_b[1];
      const float m = fmaxf(l0, l1);
      const float e0 = __expf(l0 - m), e1 = __expf(l1 - m);
      const float s = e0 + e1;
      out[b * 2 + 0] = e0 / s;
      out[b * 2 + 1] = e1 / s;
    }
    for (int i = 0; i < 4; ++i) out[8 + i] = (float)labels[i];
  }
}

extern "C" void kernel_launch(void* const* d_in, const int* in_sizes, int n_in,
                              void* d_out, int out_size, void* d_ws, size_t ws_size,
                              hipStream_t stream) {
  const float* x       = (const float*)d_in[0];
  const float* hx0     = (const float*)d_in[1];
  const int*   labels  = (const int*)d_in[2];
  const float* conv1_w = (const float*)d_in[3];
  const float* conv1_b = (const float*)d_in[4];
  const float* conv2_w = (const float*)d_in[5];
  const float* conv2_b = (const float*)d_in[6];
  const float* w_ih    = (const float*)d_in[7];
  const float* w_hh    = (const float*)d_in[8];
  const float* b_ih    = (const float*)d_in[9];
  const float* b_hh    = (const float*)d_in[10];
  const float* fc_w    = (const float*)d_in[11];
  const float* fc_b    = (const float*)d_in[12];

  char* ws = (char*)d_ws;
  size_t off = 0;
  unsigned short* pool1 = (unsigned short*)(ws + off); off += (size_t)128 * 84 * 41 * 64 * 2;  // 56.4MB
  unsigned short* feat_bf = (unsigned short*)(ws + off); off += (size_t)128 * KP * 2;          // 0.5MB
  float* gi    = (float*)(ws + off); off += (size_t)128 * 5880 * 4;                            // 3.0MB
  unsigned short* whh_bf = (unsigned short*)(ws + off); off += (size_t)5880 * 1960 * 2;        // 23.0MB
  unsigned short* wih_bf = (unsigned short*)(ws + off); off += (size_t)NP * KP * 2;            // 23.4MB
  float* h0    = (float*)(ws + off); off += (size_t)4 * 1960 * 4;
  float* h1    = (float*)(ws + off); off += (size_t)4 * 1960 * 4;
  unsigned short* w1f = (unsigned short*)(ws + off); off += (size_t)4 * 4 * 64 * 8 * 2;        // 16KB
  unsigned short* w2f = (unsigned short*)(ws + off); off += (size_t)32 * 64 * 8 * 2;           // 32KB

  k_cvt<<<2048, 256, 0, stream>>>(w_hh, whh_bf, 5880 * 1960 / 4);
  k_cvt_wih<<<(NP * KP / 8 + 255) / 256, 256, 0, stream>>>(w_ih, wih_bf);
  k_w1frag<<<32, 256, 0, stream>>>(conv1_w, w1f);
  k_w2frag<<<64, 256, 0, stream>>>(conv2_w, w2f);
  k_featpad<<<1, 256, 0, stream>>>(feat_bf);

  dim3 g1(128, 21);
  k_conv1<<<g1, 256, 0, stream>>>(x, w1f, conv1_b, pool1);

  dim3 g2(128, 14);
  k_conv2<<<g2, 128, 0, stream>>>(pool1, w2f, conv2_b, feat_bf);

  dim3 g3(368, 2);
  k_gi<<<g3, 256, 0, stream>>>(feat_bf, wih_bf, b_ih, gi);

  // all 32 GRU steps in one cooperative launch; final h in h0 (t=31 odd writes h0)
  void* gru_args[] = {(void*)&whh_bf, (void*)&b_hh, (void*)&gi, (void*)&hx0,
                      (void*)&h0, (void*)&h1};
  hipLaunchCooperativeKernel((const void*)k_gru, dim3(245), dim3(768), gru_args, 0, stream);

  k_fc<<<1, 64, 0, stream>>>(h0, fc_w, fc_b, labels, (float*)d_out);
}

// Round 7
// 777.293 us; speedup vs baseline: 2.0579x; 2.0579x over previous
//
#include <hip/hip_runtime.h>
#include <hip/hip_cooperative_groups.h>

// ---------- helpers ----------
__device__ __forceinline__ float bf2f(unsigned short u) {
  union { unsigned int i; float f; } v; v.i = ((unsigned int)u) << 16; return v.f;
}
__device__ __forceinline__ unsigned short f2bf(float f) {
  union { float f; unsigned int i; } v; v.f = f;
  unsigned int x = v.i;
  return (unsigned short)((x + 0x7fffu + ((x >> 16) & 1u)) >> 16);
}
__device__ __forceinline__ float sigmf(float x) { return 1.f / (1.f + __expf(-x)); }

typedef float f32x4 __attribute__((ext_vector_type(4)));
typedef short short8v __attribute__((ext_vector_type(8)));
typedef short short4v __attribute__((ext_vector_type(4)));

// pack 8 f32 -> 8 bf16 (truncate)
__device__ __forceinline__ short8v pack8(const float* p) {
  union { short8v s; unsigned int u[4]; } r;
#pragma unroll
  for (int i = 0; i < 4; ++i) {
    unsigned int lo = __float_as_uint(p[2 * i]) >> 16;
    unsigned int hi = __float_as_uint(p[2 * i + 1]) & 0xFFFF0000u;
    r.u[i] = hi | lo;
  }
  return r.s;
}

// ---------- sizes ----------
// conv1: (128,1,257,128) -> conv 253x124 -> pool3 -> (128,64,84,41)
// conv2: -> conv 85x42 -> pool3 -> (128,5,28,14) -> feat (128,1960) [bf16, KP=1984]

#define KP 1984
#define NP 5888
#define GRU_BLOCKS 245

// ---------- prep: conv1 weight fragments (uniform K=128 map) ----------
__global__ void k_w1frag(const float* __restrict__ w1, unsigned short* __restrict__ w1f) {
  int idx = blockIdx.x * 256 + threadIdx.x;
  if (idx >= 4 * 4 * 64 * 8) return;
  int j = idx & 7, l = (idx >> 3) & 63;
  int rest = idx >> 9;  // 0..15
  int s = rest & 3, ocf = rest >> 2;
  int oc = ocf * 16 + (l & 15);
  int k = s * 32 + (l >> 4) * 8 + j;
  float v = 0.f;
  if (k < 108) {
    int fr = k / 12, fc = k - fr * 12;
    if (fc < 9) v = w1[oc * 81 + fr * 9 + fc];
  }
  w1f[idx] = f2bf(v);
}

// ---------- prep: conv2 weight fragments ----------
__global__ void k_w2frag(const float* __restrict__ w2, unsigned short* __restrict__ w2f) {
  int idx = blockIdx.x * 256 + threadIdx.x;
  if (idx >= 32 * 64 * 8) return;
  int j = idx & 7, l = (idx >> 3) & 63, s = idx >> 9;
  int oc = l & 15;
  int k = s * 32 + (l >> 4) * 8 + j;
  int t = k >> 6, ch = k & 63, fr = t >> 2, fc = t & 3;
  float v = (oc < 5) ? w2[((oc * 64 + ch) * 4 + fr) * 4 + fc] : 0.f;
  w2f[idx] = f2bf(v);
}

// ---------- prep: w_ih f32 [5880][1960] -> bf16 [5888][1984] zero-padded ----------
__global__ void k_cvt_wih(const float* __restrict__ src, unsigned short* __restrict__ dst) {
  const int total = NP * KP / 8;
  int idx = blockIdx.x * 256 + threadIdx.x;
  if (idx >= total) return;
  int row = idx / (KP / 8);
  int c8 = (idx - row * (KP / 8)) * 8;
  short8v v = {0, 0, 0, 0, 0, 0, 0, 0};
  if (row < 5880 && c8 < 1960) {
    const float* s = src + (size_t)row * 1960 + c8;
    if (c8 + 8 <= 1960) {
      float tmp[8];
#pragma unroll
      for (int i = 0; i < 8; ++i) tmp[i] = s[i];
      v = pack8(tmp);
    } else {
      union { short8v s8; unsigned short us[8]; } u; u.s8 = v;
      for (int i = 0; i < 1960 - c8; ++i) u.us[i] = f2bf(s[i]);
      v = u.s8;
    }
  }
  *reinterpret_cast<short8v*>(dst + (size_t)idx * 8) = v;
}

// ---------- prep: zero feat_bf K-pad columns + GRU flags ----------
__global__ void k_featpad(unsigned short* __restrict__ feat_bf, unsigned int* __restrict__ flags) {
  for (int i = threadIdx.x; i < 128 * 24; i += 256) {
    int n = i / 24, k = 1960 + i % 24;
    feat_bf[(size_t)n * KP + k] = 0;
  }
  for (int i = threadIdx.x; i < GRU_BLOCKS; i += 256) flags[i] = 0u;
}

// ---------- kernel 1: conv1 MFMA, uniform K=128, 4-shift-copy LDS ----------
__global__ __launch_bounds__(256) void k_conv1(const float* __restrict__ x,
                                               const unsigned short* __restrict__ w1f,
                                               const float* __restrict__ b1,
                                               unsigned short* __restrict__ pool1) {
  const int n = blockIdx.x, qrg = blockIdx.y;
  const int b = n >> 5, w = n & 31;
  __shared__ __align__(16) unsigned short s_b[4 * 22 * 140];
  const int tid = threadIdx.x;
  for (int i = tid; i < 22 * 144; i += 256) {
    int lr = i / 144, lc = i - lr * 144;
    int f = 12 * qrg + lr - 2;
    int t = lc - 2;
    float v = 0.f;
    if (lr < 20 && f >= 0 && f < 257 && t >= 0 && t < 128)
      v = x[((size_t)b * 258 + 1 + f) * 2176 + w * 64 + t];
    unsigned short bf = f2bf(v);
#pragma unroll
    for (int m = 0; m < 4; ++m) {
      int d = lc + m;
      if (d < 140) s_b[m * 3080 + lr * 140 + d] = bf;
    }
  }
  const int lane = tid & 63, wv = tid >> 6;
  short8v bw[4][4];
#pragma unroll
  for (int ocf = 0; ocf < 4; ++ocf)
#pragma unroll
    for (int s = 0; s < 4; ++s)
      bw[ocf][s] = *reinterpret_cast<const short8v*>(&w1f[((ocf * 4 + s) * 64 + lane) * 8]);
  __syncthreads();

  const int li = lane & 15, g = lane >> 4;
  int fr0s[4], fc0s[4], is8s[4];
#pragma unroll
  for (int s = 0; s < 4; ++s) {
    int k0 = 32 * s + 8 * g;
    int fr = k0 / 12;
    int fc = k0 - fr * 12;
    fr0s[s] = fr; fc0s[s] = fc; is8s[s] = (fc == 8);
  }
  float bv[4];
#pragma unroll
  for (int ocf = 0; ocf < 4; ++ocf) bv[ocf] = b1[ocf * 16 + li];

  const int qr = qrg * 4 + wv;

  for (int pgt = 0; pgt < 3; ++pgt) {
    int pg = pgt * 16 + li;
    if (pg > 40) pg = 40;
    const int c0 = 3 * pg;
    int RA[3][4], RB[3][4];
#pragma unroll
    for (int phi = 0; phi < 3; ++phi) {
#pragma unroll
      for (int s = 0; s < 4; ++s) {
        int cc = c0 + phi + fc0s[s];
        int m = (-cc) & 3;
        RA[phi][s] = m * 3080 + fr0s[s] * 140 + cc + m;
        int cc2 = c0 + phi;
        int m2 = (-cc2) & 3;
        int rb8 = m2 * 3080 + (fr0s[s] + 1) * 140 + cc2 + m2;
        RB[phi][s] = is8s[s] ? rb8 : (RA[phi][s] + 4);
      }
    }
    f32x4 pm[4];
#pragma unroll
    for (int ocf = 0; ocf < 4; ++ocf) pm[ocf] = (f32x4){-3.4e38f, -3.4e38f, -3.4e38f, -3.4e38f};

    for (int rr = 0; rr < 3; ++rr) {
      const int ro = (3 * wv + rr) * 140;
#pragma unroll
      for (int phi = 0; phi < 3; ++phi) {
        f32x4 acc[4];
#pragma unroll
        for (int ocf = 0; ocf < 4; ++ocf) acc[ocf] = (f32x4){0.f, 0.f, 0.f, 0.f};
#pragma unroll
        for (int s = 0; s < 4; ++s) {
          short4v lo = *reinterpret_cast<const short4v*>(&s_b[ro + RA[phi][s]]);
          short4v hi = *reinterpret_cast<const short4v*>(&s_b[ro + RB[phi][s]]);
          short8v a = __builtin_shufflevector(lo, hi, 0, 1, 2, 3, 4, 5, 6, 7);
#pragma unroll
          for (int ocf = 0; ocf < 4; ++ocf)
            acc[ocf] = __builtin_amdgcn_mfma_f32_16x16x32_bf16(a, bw[ocf][s], acc[ocf], 0, 0, 0);
        }
#pragma unroll
        for (int ocf = 0; ocf < 4; ++ocf) {
#pragma unroll
          for (int i = 0; i < 4; ++i) pm[ocf][i] = fmaxf(pm[ocf][i], acc[ocf][i]);
        }
      }
    }
#pragma unroll
    for (int ocf = 0; ocf < 4; ++ocf) {
#pragma unroll
      for (int i = 0; i < 4; ++i) {
        int pg2 = pgt * 16 + g * 4 + i;
        if (pg2 <= 40) {
          int oc = ocf * 16 + li;
          pool1[(((size_t)n * 84 + qr) * 41 + pg2) * 64 + oc] = f2bf(sigmf(pm[ocf][i] + bv[ocf]));
        }
      }
    }
  }
}

// ---------- kernel 2: conv2 MFMA, LDS-staged A, weights in regs ----------
__global__ __launch_bounds__(128, 2) void k_conv2(const unsigned short* __restrict__ pool1,
                                                  const unsigned short* __restrict__ w2f,
                                                  const float* __restrict__ b2,
                                                  unsigned short* __restrict__ feat_bf) {
  const int n = blockIdx.x, qg = blockIdx.y;
  __shared__ __align__(16) unsigned short s_a[9 * 46 * 64];
  const int tid = threadIdx.x;
  const int lane = tid & 63, wv = tid >> 6;
  short8v bwr[32];
#pragma unroll
  for (int s = 0; s < 32; ++s)
    bwr[s] = *reinterpret_cast<const short8v*>(&w2f[(s * 64 + lane) * 8]);
  const int r0 = 6 * qg - 2;
  for (int idx = tid; idx < 9 * 46 * 8; idx += 128) {
    int row = idx / (46 * 8);
    int rem = idx - row * (46 * 8);
    int lc = rem >> 3, cp = rem & 7;
    int gr = r0 + row, gc = lc - 2;
    short8v v = {0, 0, 0, 0, 0, 0, 0, 0};
    if ((unsigned)gr < 84u && (unsigned)gc < 41u)
      v = *reinterpret_cast<const short8v*>(&pool1[(((size_t)n * 84 + gr) * 41 + gc) * 64 + cp * 8]);
    int rot = (cp * 8 + lc * 8) & 63;
    *reinterpret_cast<short8v*>(&s_a[(row * 46 + lc) * 64 + rot]) = v;
  }
  __syncthreads();

  const int q = qg * 2 + wv;
  const int li = lane & 15, g = lane >> 4;
  const int pg = li > 13 ? 13 : li;
  f32x4 pm = (f32x4){-3.4e38f, -3.4e38f, -3.4e38f, -3.4e38f};

  for (int rr = 0; rr < 3; ++rr) {
#pragma unroll
    for (int phi = 0; phi < 3; ++phi) {
      f32x4 acc[4];
#pragma unroll
      for (int i = 0; i < 4; ++i) acc[i] = (f32x4){0.f, 0.f, 0.f, 0.f};
#pragma unroll
      for (int s = 0; s < 32; ++s) {
        const int t = s >> 1, h = s & 1;
        const int fr = t >> 2, fc = t & 3;
        const int srow = 3 * wv + rr + fr;
        const int lc = 3 * pg + phi + fc;
        const int rot = (h * 32 + g * 8 + lc * 8) & 63;
        short8v a = *reinterpret_cast<const short8v*>(&s_a[(srow * 46 + lc) * 64 + rot]);
        acc[s & 3] = __builtin_amdgcn_mfma_f32_16x16x32_bf16(a, bwr[s], acc[s & 3], 0, 0, 0);
      }
      f32x4 sum;
#pragma unroll
      for (int i = 0; i < 4; ++i) sum[i] = (acc[0][i] + acc[1][i]) + (acc[2][i] + acc[3][i]);
#pragma unroll
      for (int i = 0; i < 4; ++i) pm[i] = fmaxf(pm[i], sum[i]);
    }
  }
  if (li < 5) {
#pragma unroll
    for (int i = 0; i < 4; ++i) {
      int pq = g * 4 + i;
      if (pq < 14)
        feat_bf[(size_t)n * KP + li * 392 + q * 14 + pq] = f2bf(sigmf(pm[i] + b2[li]));
    }
  }
}

// ---------- kernel 3: f32 -> bf16 convert (w_hh) ----------
__global__ void k_cvt(const float* __restrict__ src, unsigned short* __restrict__ dst, int n4) {
  for (int i = blockIdx.x * blockDim.x + threadIdx.x; i < n4; i += gridDim.x * blockDim.x) {
    float4 v = *reinterpret_cast<const float4*>(&src[i * 4]);
    ushort4 u;
    u.x = f2bf(v.x); u.y = f2bf(v.y); u.z = f2bf(v.z); u.w = f2bf(v.w);
    *reinterpret_cast<ushort4*>(&dst[i * 4]) = u;
  }
}

// ---------- kernel 4: gi MFMA GEMM ----------
__global__ __launch_bounds__(256) void k_gi(const unsigned short* __restrict__ feat_bf,
                                            const unsigned short* __restrict__ wih_bf,
                                            const float* __restrict__ b_ih,
                                            float* __restrict__ gi) {
  const int bx = blockIdx.x, bm = blockIdx.y;
  const int w = threadIdx.x >> 6, lane = threadIdx.x & 63;
  const int li = lane & 15, g = lane >> 4;
  const unsigned short* ap = feat_bf + (size_t)(bm * 64 + w * 16 + li) * KP + g * 8;
  const unsigned short* bp = wih_bf + (size_t)(bx * 16 + li) * KP + g * 8;
  f32x4 acc0 = (f32x4){0.f, 0.f, 0.f, 0.f};
  f32x4 acc1 = (f32x4){0.f, 0.f, 0.f, 0.f};
  for (int kc = 0; kc < 62; kc += 2) {
    short8v a0 = *reinterpret_cast<const short8v*>(ap + kc * 32);
    short8v b0 = *reinterpret_cast<const short8v*>(bp + kc * 32);
    short8v a1 = *reinterpret_cast<const short8v*>(ap + kc * 32 + 32);
    short8v b1 = *reinterpret_cast<const short8v*>(bp + kc * 32 + 32);
    acc0 = __builtin_amdgcn_mfma_f32_16x16x32_bf16(a0, b0, acc0, 0, 0, 0);
    acc1 = __builtin_amdgcn_mfma_f32_16x16x32_bf16(a1, b1, acc1, 0, 0, 0);
  }
  const int j = bx * 16 + li;
  if (j < 5880) {
    const float bi = b_ih[j];
    const int n0 = bm * 64 + w * 16 + g * 4;
#pragma unroll
    for (int i = 0; i < 4; ++i)
      gi[(size_t)(n0 + i) * 5880 + j] = acc0[i] + acc1[i] + bi;
  }
}

// ---------- kernel 5: persistent GRU, LDS-resident w_hh, flag-array barrier ----------
// 245 blocks x 768 thr. Block owns k0=bid*8..+7 (24 w rows = 94KB LDS).
// LDS w layout [r][i][kq][8]: thread (kq,d) reads chunk c=kq+8i -> contiguous
// 128B per 8-lane group -> conflict-free.
// Cross-block: h via agent-scope atomics (LLC-coherent), per-block flag release,
// per-thread distinct-flag spin (no RMW contention).
__global__ __launch_bounds__(768) void k_gru(const unsigned short* __restrict__ whh,
                                             const float* __restrict__ b_hh,
                                             const float* __restrict__ gi,
                                             const float* __restrict__ hx0,
                                             float* __restrict__ h0,
                                             float* __restrict__ h1,
                                             unsigned int* __restrict__ flags) {
  __shared__ __align__(16) unsigned short s_w[24 * 31 * 8 * 8];  // 95232 B
  __shared__ float s_h[7840];
  __shared__ float s_p[96 * 8];
  __shared__ float s_gh[96];
  const int bid = blockIdx.x;
  const int tid = threadIdx.x;
  const int k0 = bid * 8;
  // preload w rows: r = g*8+kk <- whh row g*1960 + k0 + kk
  for (int idx = tid; idx < 24 * 245; idx += 768) {
    int r = idx / 245, c = idx - r * 245;
    int gg = r >> 3, kk2 = r & 7;
    short8v v = *reinterpret_cast<const short8v*>(
        whh + (size_t)(gg * 1960 + k0 + kk2) * 1960 + c * 8);
    int i = c >> 3, kq2 = c & 7;
    *reinterpret_cast<short8v*>(&s_w[((r * 31 + i) * 8 + kq2) * 8]) = v;
  }
  const int kq = tid & 7;
  const int d = tid >> 3;  // 0..95: d = g*32 + b*8 + kk
  const int kk = d & 7;
  const int b = (d >> 3) & 3;
  const int g = d >> 5;
  const int r = g * 8 + kk;
  const float* hrow = s_h + b * 1960;

  for (int t = 0; t < 32; ++t) {
    const float* hin = (t == 0) ? hx0 : ((t & 1) ? h1 : h0);
    float* hout = (t & 1) ? h0 : h1;
    if (t == 0) {
      for (int i = tid; i < 7840; i += 768) s_h[i] = hin[i];
    } else {
      for (int i = tid; i < 7840; i += 768)
        s_h[i] = __hip_atomic_load(&hin[i], __ATOMIC_RELAXED, __HIP_MEMORY_SCOPE_AGENT);
    }
    __syncthreads();
    float acc = 0.f;
#pragma unroll 4
    for (int i = 0; i < 31; ++i) {
      int c = kq + 8 * i;
      if (c < 245) {
        union { short8v s; unsigned short us[8]; } u;
        u.s = *reinterpret_cast<const short8v*>(&s_w[((r * 31 + i) * 8 + kq) * 8]);
        const float* hp = hrow + c * 8;
        float4 hv0 = *reinterpret_cast<const float4*>(hp);
        float4 hv1 = *reinterpret_cast<const float4*>(hp + 4);
        acc += bf2f(u.us[0]) * hv0.x + bf2f(u.us[1]) * hv0.y +
               bf2f(u.us[2]) * hv0.z + bf2f(u.us[3]) * hv0.w +
               bf2f(u.us[4]) * hv1.x + bf2f(u.us[5]) * hv1.y +
               bf2f(u.us[6]) * hv1.z + bf2f(u.us[7]) * hv1.w;
      }
    }
    s_p[d * 8 + kq] = acc;
    __syncthreads();
    if (tid < 96) {
      float s = 0.f;
#pragma unroll
      for (int q = 0; q < 8; ++q) s += s_p[tid * 8 + q];
      s_gh[tid] = s + b_hh[(tid >> 5) * 1960 + k0 + (tid & 7)];
    }
    __syncthreads();
    if (tid < 32) {
      const int ck = tid & 7, cb = tid >> 3;
      const int k = k0 + ck;
      const int nrow = (cb * 32 + t) * 5880;
      const float ghr = s_gh[ck + 8 * cb];
      const float ghz = s_gh[ck + 8 * cb + 32];
      const float ghn = s_gh[ck + 8 * cb + 64];
      const float rr = sigmf(gi[nrow + k] + ghr);
      const float zz = sigmf(gi[nrow + 1960 + k] + ghz);
      const float nn = tanhf(gi[nrow + 3920 + k] + rr * ghn);
      const float hp = s_h[cb * 1960 + k];
      const float hv = (1.f - zz) * nn + zz * hp;
      __hip_atomic_store(&hout[cb * 1960 + k], hv, __ATOMIC_RELAXED, __HIP_MEMORY_SCOPE_AGENT);
    }
    if (t < 31) {
      __syncthreads();  // drains vmcnt: h' stores complete before flag
      if (tid == 0)
        __hip_atomic_store(&flags[bid], (unsigned)(t + 1), __ATOMIC_RELEASE, __HIP_MEMORY_SCOPE_AGENT);
      if (tid < GRU_BLOCKS) {
        while (__hip_atomic_load(&flags[tid], __ATOMIC_RELAXED, __HIP_MEMORY_SCOPE_AGENT) <
               (unsigned)(t + 1)) {
          __builtin_amdgcn_s_sleep(1);
        }
      }
      __syncthreads();
    }
  }
}

// ---------- kernel 6: fc + softmax + labels ----------
__global__ void k_fc(const float* __restrict__ h, const float* __restrict__ fc_w,
                     const float* __restrict__ fc_b, const int* __restrict__ labels,
                     float* __restrict__ out) {
  const int l = threadIdx.x;
  float acc[8];
#pragma unroll
  for (int i = 0; i < 8; ++i) acc[i] = 0.f;
  for (int k = l; k < 1960; k += 64) {
    const float w0 = fc_w[k], w1 = fc_w[1960 + k];
#pragma unroll
    for (int b = 0; b < 4; ++b) {
      const float hv = h[b * 1960 + k];
      acc[b * 2 + 0] += hv * w0;
      acc[b * 2 + 1] += hv * w1;
    }
  }
#pragma unroll
  for (int i = 0; i < 8; ++i) {
    float a = acc[i];
#pragma unroll
    for (int off = 32; off; off >>= 1) a += __shfl_xor(a, off, 64);
    acc[i] = a;
  }
  if (l == 0) {
#pragma unroll
    for (int b = 0; b < 4; ++b) {
      const float l0 = acc[b * 2] + fc_b[0], l1 = acc[b * 2 + 1] + fc_b[1];
      const float m = fmaxf(l0, l1);
      const float e0 = __expf(l0 - m), e1 = __expf(l1 - m);
      const float s = e0 + e1;
      out[b * 2 + 0] = e0 / s;
      out[b * 2 + 1] = e1 / s;
    }
    for (int i = 0; i < 4; ++i) out[8 + i] = (float)labels[i];
  }
}

extern "C" void kernel_launch(void* const* d_in, const int* in_sizes, int n_in,
                              void* d_out, int out_size, void* d_ws, size_t ws_size,
                              hipStream_t stream) {
  const float* x       = (const float*)d_in[0];
  const float* hx0     = (const float*)d_in[1];
  const int*   labels  = (const int*)d_in[2];
  const float* conv1_w = (const float*)d_in[3];
  const float* conv1_b = (const float*)d_in[4];
  const float* conv2_w = (const float*)d_in[5];
  const float* conv2_b = (const float*)d_in[6];
  const float* w_ih    = (const float*)d_in[7];
  const float* w_hh    = (const float*)d_in[8];
  const float* b_ih    = (const float*)d_in[9];
  const float* b_hh    = (const float*)d_in[10];
  const float* fc_w    = (const float*)d_in[11];
  const float* fc_b    = (const float*)d_in[12];

  char* ws = (char*)d_ws;
  size_t off = 0;
  unsigned short* pool1 = (unsigned short*)(ws + off); off += (size_t)128 * 84 * 41 * 64 * 2;  // 56.4MB
  unsigned short* feat_bf = (unsigned short*)(ws + off); off += (size_t)128 * KP * 2;          // 0.5MB
  float* gi    = (float*)(ws + off); off += (size_t)128 * 5880 * 4;                            // 3.0MB
  unsigned short* whh_bf = (unsigned short*)(ws + off); off += (size_t)5880 * 1960 * 2;        // 23.0MB
  unsigned short* wih_bf = (unsigned short*)(ws + off); off += (size_t)NP * KP * 2;            // 23.4MB
  float* h0    = (float*)(ws + off); off += (size_t)4 * 1960 * 4;
  float* h1    = (float*)(ws + off); off += (size_t)4 * 1960 * 4;
  unsigned short* w1f = (unsigned short*)(ws + off); off += (size_t)4 * 4 * 64 * 8 * 2;        // 16KB
  unsigned short* w2f = (unsigned short*)(ws + off); off += (size_t)32 * 64 * 8 * 2;           // 32KB
  unsigned int* flags = (unsigned int*)(ws + off); off += (size_t)GRU_BLOCKS * 4;

  k_cvt<<<2048, 256, 0, stream>>>(w_hh, whh_bf, 5880 * 1960 / 4);
  k_cvt_wih<<<(NP * KP / 8 + 255) / 256, 256, 0, stream>>>(w_ih, wih_bf);
  k_w1frag<<<32, 256, 0, stream>>>(conv1_w, w1f);
  k_w2frag<<<64, 256, 0, stream>>>(conv2_w, w2f);
  k_featpad<<<1, 256, 0, stream>>>(feat_bf, flags);

  dim3 g1(128, 21);
  k_conv1<<<g1, 256, 0, stream>>>(x, w1f, conv1_b, pool1);

  dim3 g2(128, 14);
  k_conv2<<<g2, 128, 0, stream>>>(pool1, w2f, conv2_b, feat_bf);

  dim3 g3(368, 2);
  k_gi<<<g3, 256, 0, stream>>>(feat_bf, wih_bf, b_ih, gi);

  // all 32 GRU steps, persistent; final h in h0 (t=31 odd writes h0)
  void* gru_args[] = {(void*)&whh_bf, (void*)&b_hh, (void*)&gi, (void*)&hx0,
                      (void*)&h0, (void*)&h1, (void*)&flags};
  hipLaunchCooperativeKernel((const void*)k_gru, dim3(GRU_BLOCKS), dim3(768), gru_args, 0, stream);

  k_fc<<<1, 64, 0, stream>>>(h0, fc_w, fc_b, labels, (float*)d_out);
}

// Round 8
// 756.511 us; speedup vs baseline: 2.1145x; 1.0275x over previous
//
#include <hip/hip_runtime.h>
#include <hip/hip_cooperative_groups.h>

// ---------- helpers ----------
__device__ __forceinline__ float bf2f(unsigned short u) {
  union { unsigned int i; float f; } v; v.i = ((unsigned int)u) << 16; return v.f;
}
__device__ __forceinline__ unsigned short f2bf(float f) {
  union { float f; unsigned int i; } v; v.f = f;
  unsigned int x = v.i;
  return (unsigned short)((x + 0x7fffu + ((x >> 16) & 1u)) >> 16);
}
__device__ __forceinline__ float sigmf(float x) { return 1.f / (1.f + __expf(-x)); }

typedef float f32x4 __attribute__((ext_vector_type(4)));
typedef short short8v __attribute__((ext_vector_type(8)));
typedef short short4v __attribute__((ext_vector_type(4)));

// pack 8 f32 -> 8 bf16 (truncate)
__device__ __forceinline__ short8v pack8(const float* p) {
  union { short8v s; unsigned int u[4]; } r;
#pragma unroll
  for (int i = 0; i < 4; ++i) {
    unsigned int lo = __float_as_uint(p[2 * i]) >> 16;
    unsigned int hi = __float_as_uint(p[2 * i + 1]) & 0xFFFF0000u;
    r.u[i] = hi | lo;
  }
  return r.s;
}

#define KP 1984
#define NP 5888
#define GRU_BLOCKS 245

// ---------- prep: conv1 weight fragments (uniform K=128 map) ----------
__global__ void k_w1frag(const float* __restrict__ w1, unsigned short* __restrict__ w1f) {
  int idx = blockIdx.x * 256 + threadIdx.x;
  if (idx >= 4 * 4 * 64 * 8) return;
  int j = idx & 7, l = (idx >> 3) & 63;
  int rest = idx >> 9;  // 0..15
  int s = rest & 3, ocf = rest >> 2;
  int oc = ocf * 16 + (l & 15);
  int k = s * 32 + (l >> 4) * 8 + j;
  float v = 0.f;
  if (k < 108) {
    int fr = k / 12, fc = k - fr * 12;
    if (fc < 9) v = w1[oc * 81 + fr * 9 + fc];
  }
  w1f[idx] = f2bf(v);
}

// ---------- prep: conv2 weight fragments ----------
__global__ void k_w2frag(const float* __restrict__ w2, unsigned short* __restrict__ w2f) {
  int idx = blockIdx.x * 256 + threadIdx.x;
  if (idx >= 32 * 64 * 8) return;
  int j = idx & 7, l = (idx >> 3) & 63, s = idx >> 9;
  int oc = l & 15;
  int k = s * 32 + (l >> 4) * 8 + j;
  int t = k >> 6, ch = k & 63, fr = t >> 2, fc = t & 3;
  float v = (oc < 5) ? w2[((oc * 64 + ch) * 4 + fr) * 4 + fc] : 0.f;
  w2f[idx] = f2bf(v);
}

// ---------- prep: w_ih f32 -> bf16 [5888][1984] zero-padded ----------
__global__ void k_cvt_wih(const float* __restrict__ src, unsigned short* __restrict__ dst) {
  const int total = NP * KP / 8;
  int idx = blockIdx.x * 256 + threadIdx.x;
  if (idx >= total) return;
  int row = idx / (KP / 8);
  int c8 = (idx - row * (KP / 8)) * 8;
  short8v v = {0, 0, 0, 0, 0, 0, 0, 0};
  if (row < 5880 && c8 < 1960) {
    const float* s = src + (size_t)row * 1960 + c8;
    if (c8 + 8 <= 1960) {
      float tmp[8];
#pragma unroll
      for (int i = 0; i < 8; ++i) tmp[i] = s[i];
      v = pack8(tmp);
    } else {
      union { short8v s8; unsigned short us[8]; } u; u.s8 = v;
      for (int i = 0; i < 1960 - c8; ++i) u.us[i] = f2bf(s[i]);
      v = u.s8;
    }
  }
  *reinterpret_cast<short8v*>(dst + (size_t)idx * 8) = v;
}

// ---------- prep: zero feat_bf K-pad columns + GRU flags ----------
__global__ void k_featpad(unsigned short* __restrict__ feat_bf, unsigned int* __restrict__ flags) {
  for (int i = threadIdx.x; i < 128 * 24; i += 256) {
    int n = i / 24, k = 1960 + i % 24;
    feat_bf[(size_t)n * KP + k] = 0;
  }
  for (int i = threadIdx.x; i < GRU_BLOCKS; i += 256) flags[i] = 0u;
}

// ---------- kernel 1: conv1 MFMA, uniform K=128, 4-shift-copy LDS ----------
__global__ __launch_bounds__(256) void k_conv1(const float* __restrict__ x,
                                               const unsigned short* __restrict__ w1f,
                                               const float* __restrict__ b1,
                                               unsigned short* __restrict__ pool1) {
  const int n = blockIdx.x, qrg = blockIdx.y;
  const int b = n >> 5, w = n & 31;
  __shared__ __align__(16) unsigned short s_b[4 * 22 * 140];
  const int tid = threadIdx.x;
  for (int i = tid; i < 22 * 144; i += 256) {
    int lr = i / 144, lc = i - lr * 144;
    int f = 12 * qrg + lr - 2;
    int t = lc - 2;
    float v = 0.f;
    if (lr < 20 && f >= 0 && f < 257 && t >= 0 && t < 128)
      v = x[((size_t)b * 258 + 1 + f) * 2176 + w * 64 + t];
    unsigned short bf = f2bf(v);
#pragma unroll
    for (int m = 0; m < 4; ++m) {
      int d = lc + m;
      if (d < 140) s_b[m * 3080 + lr * 140 + d] = bf;
    }
  }
  const int lane = tid & 63, wv = tid >> 6;
  short8v bw[4][4];
#pragma unroll
  for (int ocf = 0; ocf < 4; ++ocf)
#pragma unroll
    for (int s = 0; s < 4; ++s)
      bw[ocf][s] = *reinterpret_cast<const short8v*>(&w1f[((ocf * 4 + s) * 64 + lane) * 8]);
  __syncthreads();

  const int li = lane & 15, g = lane >> 4;
  int fr0s[4], fc0s[4], is8s[4];
#pragma unroll
  for (int s = 0; s < 4; ++s) {
    int k0 = 32 * s + 8 * g;
    int fr = k0 / 12;
    int fc = k0 - fr * 12;
    fr0s[s] = fr; fc0s[s] = fc; is8s[s] = (fc == 8);
  }
  float bv[4];
#pragma unroll
  for (int ocf = 0; ocf < 4; ++ocf) bv[ocf] = b1[ocf * 16 + li];

  const int qr = qrg * 4 + wv;

  for (int pgt = 0; pgt < 3; ++pgt) {
    int pg = pgt * 16 + li;
    if (pg > 40) pg = 40;
    const int c0 = 3 * pg;
    int RA[3][4], RB[3][4];
#pragma unroll
    for (int phi = 0; phi < 3; ++phi) {
#pragma unroll
      for (int s = 0; s < 4; ++s) {
        int cc = c0 + phi + fc0s[s];
        int m = (-cc) & 3;
        RA[phi][s] = m * 3080 + fr0s[s] * 140 + cc + m;
        int cc2 = c0 + phi;
        int m2 = (-cc2) & 3;
        int rb8 = m2 * 3080 + (fr0s[s] + 1) * 140 + cc2 + m2;
        RB[phi][s] = is8s[s] ? rb8 : (RA[phi][s] + 4);
      }
    }
    f32x4 pm[4];
#pragma unroll
    for (int ocf = 0; ocf < 4; ++ocf) pm[ocf] = (f32x4){-3.4e38f, -3.4e38f, -3.4e38f, -3.4e38f};

    for (int rr = 0; rr < 3; ++rr) {
      const int ro = (3 * wv + rr) * 140;
#pragma unroll
      for (int phi = 0; phi < 3; ++phi) {
        f32x4 acc[4];
#pragma unroll
        for (int ocf = 0; ocf < 4; ++ocf) acc[ocf] = (f32x4){0.f, 0.f, 0.f, 0.f};
#pragma unroll
        for (int s = 0; s < 4; ++s) {
          short4v lo = *reinterpret_cast<const short4v*>(&s_b[ro + RA[phi][s]]);
          short4v hi = *reinterpret_cast<const short4v*>(&s_b[ro + RB[phi][s]]);
          short8v a = __builtin_shufflevector(lo, hi, 0, 1, 2, 3, 4, 5, 6, 7);
#pragma unroll
          for (int ocf = 0; ocf < 4; ++ocf)
            acc[ocf] = __builtin_amdgcn_mfma_f32_16x16x32_bf16(a, bw[ocf][s], acc[ocf], 0, 0, 0);
        }
#pragma unroll
        for (int ocf = 0; ocf < 4; ++ocf) {
#pragma unroll
          for (int i = 0; i < 4; ++i) pm[ocf][i] = fmaxf(pm[ocf][i], acc[ocf][i]);
        }
      }
    }
#pragma unroll
    for (int ocf = 0; ocf < 4; ++ocf) {
#pragma unroll
      for (int i = 0; i < 4; ++i) {
        int pg2 = pgt * 16 + g * 4 + i;
        if (pg2 <= 40) {
          int oc = ocf * 16 + li;
          pool1[(((size_t)n * 84 + qr) * 41 + pg2) * 64 + oc] = f2bf(sigmf(pm[ocf][i] + bv[ocf]));
        }
      }
    }
  }
}

// ---------- kernel 2: conv2 MFMA, LDS-staged A, weights in regs ----------
__global__ __launch_bounds__(128, 2) void k_conv2(const unsigned short* __restrict__ pool1,
                                                  const unsigned short* __restrict__ w2f,
                                                  const float* __restrict__ b2,
                                                  unsigned short* __restrict__ feat_bf) {
  const int n = blockIdx.x, qg = blockIdx.y;
  __shared__ __align__(16) unsigned short s_a[9 * 46 * 64];
  const int tid = threadIdx.x;
  const int lane = tid & 63, wv = tid >> 6;
  short8v bwr[32];
#pragma unroll
  for (int s = 0; s < 32; ++s)
    bwr[s] = *reinterpret_cast<const short8v*>(&w2f[(s * 64 + lane) * 8]);
  const int r0 = 6 * qg - 2;
  for (int idx = tid; idx < 9 * 46 * 8; idx += 128) {
    int row = idx / (46 * 8);
    int rem = idx - row * (46 * 8);
    int lc = rem >> 3, cp = rem & 7;
    int gr = r0 + row, gc = lc - 2;
    short8v v = {0, 0, 0, 0, 0, 0, 0, 0};
    if ((unsigned)gr < 84u && (unsigned)gc < 41u)
      v = *reinterpret_cast<const short8v*>(&pool1[(((size_t)n * 84 + gr) * 41 + gc) * 64 + cp * 8]);
    int rot = (cp * 8 + lc * 8) & 63;
    *reinterpret_cast<short8v*>(&s_a[(row * 46 + lc) * 64 + rot]) = v;
  }
  __syncthreads();

  const int q = qg * 2 + wv;
  const int li = lane & 15, g = lane >> 4;
  const int pg = li > 13 ? 13 : li;
  f32x4 pm = (f32x4){-3.4e38f, -3.4e38f, -3.4e38f, -3.4e38f};

  for (int rr = 0; rr < 3; ++rr) {
#pragma unroll
    for (int phi = 0; phi < 3; ++phi) {
      f32x4 acc[4];
#pragma unroll
      for (int i = 0; i < 4; ++i) acc[i] = (f32x4){0.f, 0.f, 0.f, 0.f};
#pragma unroll
      for (int s = 0; s < 32; ++s) {
        const int t = s >> 1, h = s & 1;
        const int fr = t >> 2, fc = t & 3;
        const int srow = 3 * wv + rr + fr;
        const int lc = 3 * pg + phi + fc;
        const int rot = (h * 32 + g * 8 + lc * 8) & 63;
        short8v a = *reinterpret_cast<const short8v*>(&s_a[(srow * 46 + lc) * 64 + rot]);
        acc[s & 3] = __builtin_amdgcn_mfma_f32_16x16x32_bf16(a, bwr[s], acc[s & 3], 0, 0, 0);
      }
      f32x4 sum;
#pragma unroll
      for (int i = 0; i < 4; ++i) sum[i] = (acc[0][i] + acc[1][i]) + (acc[2][i] + acc[3][i]);
#pragma unroll
      for (int i = 0; i < 4; ++i) pm[i] = fmaxf(pm[i], sum[i]);
    }
  }
  if (li < 5) {
#pragma unroll
    for (int i = 0; i < 4; ++i) {
      int pq = g * 4 + i;
      if (pq < 14)
        feat_bf[(size_t)n * KP + li * 392 + q * 14 + pq] = f2bf(sigmf(pm[i] + b2[li]));
    }
  }
}

// ---------- kernel 3: f32 -> bf16 convert (w_hh) ----------
__global__ void k_cvt(const float* __restrict__ src, unsigned short* __restrict__ dst, int n4) {
  for (int i = blockIdx.x * blockDim.x + threadIdx.x; i < n4; i += gridDim.x * blockDim.x) {
    float4 v = *reinterpret_cast<const float4*>(&src[i * 4]);
    ushort4 u;
    u.x = f2bf(v.x); u.y = f2bf(v.y); u.z = f2bf(v.z); u.w = f2bf(v.w);
    *reinterpret_cast<ushort4*>(&dst[i * 4]) = u;
  }
}

// ---------- kernel 4: gi MFMA GEMM ----------
__global__ __launch_bounds__(256) void k_gi(const unsigned short* __restrict__ feat_bf,
                                            const unsigned short* __restrict__ wih_bf,
                                            const float* __restrict__ b_ih,
                                            float* __restrict__ gi) {
  const int bx = blockIdx.x, bm = blockIdx.y;
  const int w = threadIdx.x >> 6, lane = threadIdx.x & 63;
  const int li = lane & 15, g = lane >> 4;
  const unsigned short* ap = feat_bf + (size_t)(bm * 64 + w * 16 + li) * KP + g * 8;
  const unsigned short* bp = wih_bf + (size_t)(bx * 16 + li) * KP + g * 8;
  f32x4 acc0 = (f32x4){0.f, 0.f, 0.f, 0.f};
  f32x4 acc1 = (f32x4){0.f, 0.f, 0.f, 0.f};
  for (int kc = 0; kc < 62; kc += 2) {
    short8v a0 = *reinterpret_cast<const short8v*>(ap + kc * 32);
    short8v b0 = *reinterpret_cast<const short8v*>(bp + kc * 32);
    short8v a1 = *reinterpret_cast<const short8v*>(ap + kc * 32 + 32);
    short8v b1 = *reinterpret_cast<const short8v*>(bp + kc * 32 + 32);
    acc0 = __builtin_amdgcn_mfma_f32_16x16x32_bf16(a0, b0, acc0, 0, 0, 0);
    acc1 = __builtin_amdgcn_mfma_f32_16x16x32_bf16(a1, b1, acc1, 0, 0, 0);
  }
  const int j = bx * 16 + li;
  if (j < 5880) {
    const float bi = b_ih[j];
    const int n0 = bm * 64 + w * 16 + g * 4;
#pragma unroll
    for (int i = 0; i < 4; ++i)
      gi[(size_t)(n0 + i) * 5880 + j] = acc0[i] + acc1[i] + bi;
  }
}

// ---------- kernel 5: persistent GRU, MFMA dot, LDS w-fragments ----------
// 245 blocks x 256 thr (4 waves). Block owns k0=bid*8 (24 j-rows = 3 gates x 8 k).
// s_w: A-fragments [mt(2)][kc(62)][lane(64)][8] bf16 = 124KB.
// h bf16 [4][1984] in LDS = B operand (lane li -> batch li&3).
// D[m=j-row][n=batch]: col=lane&15, row=(lane>>4)*4+i.
// Recurrent z*h path stays f32 in update-thread registers (block-local slice).
__global__ __launch_bounds__(256) void k_gru(const unsigned short* __restrict__ whh,
                                             const float* __restrict__ b_hh,
                                             const float* __restrict__ gi,
                                             const float* __restrict__ hx0,
                                             unsigned short* __restrict__ hb0,
                                             unsigned short* __restrict__ hb1,
                                             unsigned int* __restrict__ flags) {
  __shared__ __align__(16) unsigned short s_w[2 * 62 * 64 * 8];  // 126976 B
  __shared__ __align__(16) unsigned short s_h[4 * 1984];         // 15872 B
  __shared__ float s_part[4 * 2 * 64 * 4];                        // 8192 B
  __shared__ float s_gh[96];
  __shared__ float s_gi[96];
  const int tid = threadIdx.x;
  const int bid = blockIdx.x;
  const int k0 = bid * 8;
  const int lane = tid & 63, wv = tid >> 6;
  const int li = lane & 15, g2 = lane >> 4;

  // preload w A-fragments
  for (int idx = tid; idx < 2 * 62 * 64; idx += 256) {
    int mt = idx / 3968;
    int rem = idx - mt * 3968;
    int kc = rem >> 6, l = rem & 63;
    int lli = l & 15, lg2 = l >> 4;
    int k = kc * 32 + lg2 * 8;
    short8v v = {0, 0, 0, 0, 0, 0, 0, 0};
    bool rowok = (mt == 0) ? true : (lli < 8);
    if (rowok && k < 1960) {
      int g = (mt == 0) ? (lli >> 3) : 2;
      int kk = (mt == 0) ? (lli & 7) : lli;
      v = *reinterpret_cast<const short8v*>(&whh[(size_t)(g * 1960 + k0 + kk) * 1960 + k]);
    }
    *reinterpret_cast<short8v*>(&s_w[(size_t)idx * 8]) = v;
  }
  // zero s_h once (K-pad region stays zero; data region re-staged per step)
  for (int i = tid; i < 4 * 992; i += 256) reinterpret_cast<unsigned int*>(s_h)[i] = 0u;

  // update-thread state: tid<16 handles (cb = tid>>2, pair p = tid&3) -> k = k0+2p, k0+2p+1
  float hp0 = 0.f, hp1 = 0.f, bhr0 = 0, bhr1 = 0, bhz0 = 0, bhz1 = 0, bhn0 = 0, bhn1 = 0;
  if (tid < 16) {
    int cb = tid >> 2, p = tid & 3;
    int k = k0 + 2 * p;
    hp0 = hx0[cb * 1960 + k];
    hp1 = hx0[cb * 1960 + k + 1];
    bhr0 = b_hh[k];         bhr1 = b_hh[k + 1];
    bhz0 = b_hh[1960 + k];  bhz1 = b_hh[1960 + k + 1];
    bhn0 = b_hh[3920 + k];  bhn1 = b_hh[3920 + k + 1];
  }
  __syncthreads();

  for (int t = 0; t < 32; ++t) {
    // stage h (bf16) + prefetch gi
    if (t == 0) {
      for (int i = tid; i < 7840; i += 256) {
        int b = i / 1960, k = i - b * 1960;
        s_h[b * 1984 + k] = f2bf(hx0[i]);
      }
    } else {
      const unsigned int* hin = (const unsigned int*)((t & 1) ? hb1 : hb0);
      for (int i = tid; i < 3920; i += 256) {
        unsigned int v = __hip_atomic_load(&hin[i], __ATOMIC_RELAXED, __HIP_MEMORY_SCOPE_AGENT);
        int b = i / 980, kp = i - b * 980;
        reinterpret_cast<unsigned int*>(s_h)[b * 992 + kp] = v;
      }
    }
    if (tid < 96) {
      int gg = tid >> 5, bb = (tid >> 3) & 3, kk = tid & 7;
      s_gi[tid] = gi[(size_t)(bb * 32 + t) * 5880 + gg * 1960 + k0 + kk];
    }
    __syncthreads();

    // MFMA dot: wave wv handles kc = wv, wv+4, ...
    f32x4 acc0 = (f32x4){0.f, 0.f, 0.f, 0.f};
    f32x4 acc1 = (f32x4){0.f, 0.f, 0.f, 0.f};
    for (int kc = wv; kc < 62; kc += 4) {
      short8v bfr = *reinterpret_cast<const short8v*>(&s_h[(li & 3) * 1984 + kc * 32 + g2 * 8]);
      short8v a0 = *reinterpret_cast<const short8v*>(&s_w[((size_t)kc * 64 + lane) * 8]);
      short8v a1 = *reinterpret_cast<const short8v*>(&s_w[((size_t)(62 + kc) * 64 + lane) * 8]);
      acc0 = __builtin_amdgcn_mfma_f32_16x16x32_bf16(a0, bfr, acc0, 0, 0, 0);
      acc1 = __builtin_amdgcn_mfma_f32_16x16x32_bf16(a1, bfr, acc1, 0, 0, 0);
    }
    *reinterpret_cast<f32x4*>(&s_part[((wv * 2 + 0) * 64 + lane) * 4]) = acc0;
    *reinterpret_cast<f32x4*>(&s_part[((wv * 2 + 1) * 64 + lane) * 4]) = acc1;
    __syncthreads();

    // reduce 4 waves -> s_gh[g*32 + b*8 + kk]
    if (tid < 128) {
      int mt = tid >> 6, l2 = tid & 63;
      int n = l2 & 15, rb = (l2 >> 4) * 4;
      if (n < 4) {
#pragma unroll
        for (int i = 0; i < 4; ++i) {
          int m = rb + i;
          bool ok = (mt == 0) ? true : (m < 8);
          if (ok) {
            float s = s_part[((0 * 2 + mt) * 64 + l2) * 4 + i] +
                      s_part[((1 * 2 + mt) * 64 + l2) * 4 + i] +
                      s_part[((2 * 2 + mt) * 64 + l2) * 4 + i] +
                      s_part[((3 * 2 + mt) * 64 + l2) * 4 + i];
            int g = (mt == 0) ? (m >> 3) : 2;
            int kk = (mt == 0) ? (m & 7) : m;
            s_gh[g * 32 + n * 8 + kk] = s;
          }
        }
      }
    }
    __syncthreads();

    // update: 16 threads, 2 k each, packed u32 bf16 store
    unsigned short* hout = (t & 1) ? hb0 : hb1;
    if (tid < 16) {
      int cb = tid >> 2, p = tid & 3;
      int kk = 2 * p;
      float r0 = sigmf(s_gi[cb * 8 + kk] + s_gh[cb * 8 + kk] + bhr0);
      float z0 = sigmf(s_gi[32 + cb * 8 + kk] + s_gh[32 + cb * 8 + kk] + bhz0);
      float n0 = tanhf(s_gi[64 + cb * 8 + kk] + r0 * (s_gh[64 + cb * 8 + kk] + bhn0));
      float h0v = (1.f - z0) * n0 + z0 * hp0;
      float r1 = sigmf(s_gi[cb * 8 + kk + 1] + s_gh[cb * 8 + kk + 1] + bhr1);
      float z1 = sigmf(s_gi[32 + cb * 8 + kk + 1] + s_gh[32 + cb * 8 + kk + 1] + bhz1);
      float n1 = tanhf(s_gi[64 + cb * 8 + kk + 1] + r1 * (s_gh[64 + cb * 8 + kk + 1] + bhn1));
      float h1v = (1.f - z1) * n1 + z1 * hp1;
      hp0 = h0v; hp1 = h1v;
      unsigned int packed = (unsigned)f2bf(h0v) | ((unsigned)f2bf(h1v) << 16);
      unsigned int* dst = (unsigned int*)hout + (cb * 980 + (k0 >> 1) + p);
      __hip_atomic_store(dst, packed, __ATOMIC_RELAXED, __HIP_MEMORY_SCOPE_AGENT);
    }
    if (t < 31) {
      __syncthreads();  // drain h' stores before flag
      if (tid == 0)
        __hip_atomic_store(&flags[bid], (unsigned)(t + 1), __ATOMIC_RELEASE, __HIP_MEMORY_SCOPE_AGENT);
      if (tid < GRU_BLOCKS) {
        while (__hip_atomic_load(&flags[tid], __ATOMIC_RELAXED, __HIP_MEMORY_SCOPE_AGENT) <
               (unsigned)(t + 1)) {
          __builtin_amdgcn_s_sleep(1);
        }
      }
      __syncthreads();
    }
  }
}

// ---------- kernel 6: fc + softmax + labels (bf16 h) ----------
__global__ void k_fc(const unsigned short* __restrict__ h, const float* __restrict__ fc_w,
                     const float* __restrict__ fc_b, const int* __restrict__ labels,
                     float* __restrict__ out) {
  const int l = threadIdx.x;
  float acc[8];
#pragma unroll
  for (int i = 0; i < 8; ++i) acc[i] = 0.f;
  for (int k = l; k < 1960; k += 64) {
    const float w0 = fc_w[k], w1 = fc_w[1960 + k];
#pragma unroll
    for (int b = 0; b < 4; ++b) {
      const float hv = bf2f(h[b * 1960 + k]);
      acc[b * 2 + 0] += hv * w0;
      acc[b * 2 + 1] += hv * w1;
    }
  }
#pragma unroll
  for (int i = 0; i < 8; ++i) {
    float a = acc[i];
#pragma unroll
    for (int off = 32; off; off >>= 1) a += __shfl_xor(a, off, 64);
    acc[i] = a;
  }
  if (l == 0) {
#pragma unroll
    for (int b = 0; b < 4; ++b) {
      const float l0 = acc[b * 2] + fc_b[0], l1 = acc[b * 2 + 1] + fc_b[1];
      const float m = fmaxf(l0, l1);
      const float e0 = __expf(l0 - m), e1 = __expf(l1 - m);
      const float s = e0 + e1;
      out[b * 2 + 0] = e0 / s;
      out[b * 2 + 1] = e1 / s;
    }
    for (int i = 0; i < 4; ++i) out[8 + i] = (float)labels[i];
  }
}

extern "C" void kernel_launch(void* const* d_in, const int* in_sizes, int n_in,
                              void* d_out, int out_size, void* d_ws, size_t ws_size,
                              hipStream_t stream) {
  const float* x       = (const float*)d_in[0];
  const float* hx0     = (const float*)d_in[1];
  const int*   labels  = (const int*)d_in[2];
  const float* conv1_w = (const float*)d_in[3];
  const float* conv1_b = (const float*)d_in[4];
  const float* conv2_w = (const float*)d_in[5];
  const float* conv2_b = (const float*)d_in[6];
  const float* w_ih    = (const float*)d_in[7];
  const float* w_hh    = (const float*)d_in[8];
  const float* b_ih    = (const float*)d_in[9];
  const float* b_hh    = (const float*)d_in[10];
  const float* fc_w    = (const float*)d_in[11];
  const float* fc_b    = (const float*)d_in[12];

  char* ws = (char*)d_ws;
  size_t off = 0;
  unsigned short* pool1 = (unsigned short*)(ws + off); off += (size_t)128 * 84 * 41 * 64 * 2;  // 56.4MB
  unsigned short* feat_bf = (unsigned short*)(ws + off); off += (size_t)128 * KP * 2;          // 0.5MB
  float* gi    = (float*)(ws + off); off += (size_t)128 * 5880 * 4;                            // 3.0MB
  unsigned short* whh_bf = (unsigned short*)(ws + off); off += (size_t)5880 * 1960 * 2;        // 23.0MB
  unsigned short* wih_bf = (unsigned short*)(ws + off); off += (size_t)NP * KP * 2;            // 23.4MB
  unsigned short* hb0 = (unsigned short*)(ws + off); off += (size_t)4 * 1960 * 2 + 32;
  unsigned short* hb1 = (unsigned short*)(ws + off); off += (size_t)4 * 1960 * 2 + 32;
  unsigned short* w1f = (unsigned short*)(ws + off); off += (size_t)4 * 4 * 64 * 8 * 2;        // 16KB
  unsigned short* w2f = (unsigned short*)(ws + off); off += (size_t)32 * 64 * 8 * 2;           // 32KB
  unsigned int* flags = (unsigned int*)(ws + off); off += (size_t)GRU_BLOCKS * 4;

  k_cvt<<<2048, 256, 0, stream>>>(w_hh, whh_bf, 5880 * 1960 / 4);
  k_cvt_wih<<<(NP * KP / 8 + 255) / 256, 256, 0, stream>>>(w_ih, wih_bf);
  k_w1frag<<<32, 256, 0, stream>>>(conv1_w, w1f);
  k_w2frag<<<64, 256, 0, stream>>>(conv2_w, w2f);
  k_featpad<<<1, 256, 0, stream>>>(feat_bf, flags);

  dim3 g1(128, 21);
  k_conv1<<<g1, 256, 0, stream>>>(x, w1f, conv1_b, pool1);

  dim3 g2(128, 14);
  k_conv2<<<g2, 128, 0, stream>>>(pool1, w2f, conv2_b, feat_bf);

  dim3 g3(368, 2);
  k_gi<<<g3, 256, 0, stream>>>(feat_bf, wih_bf, b_ih, gi);

  // all 32 GRU steps, persistent MFMA; final h in hb0 (t=31 odd writes hb0)
  void* gru_args[] = {(void*)&whh_bf, (void*)&b_hh, (void*)&gi, (void*)&hx0,
                      (void*)&hb0, (void*)&hb1, (void*)&flags};
  hipLaunchCooperativeKernel((const void*)k_gru, dim3(GRU_BLOCKS), dim3(256), gru_args, 0, stream);

  k_fc<<<1, 64, 0, stream>>>(hb0, fc_w, fc_b, labels, (float*)d_out);
}

// Round 9
// 565.853 us; speedup vs baseline: 2.8269x; 1.3369x over previous
//
#include <hip/hip_runtime.h>
#include <hip/hip_cooperative_groups.h>

// ---------- helpers ----------
__device__ __forceinline__ float bf2f(unsigned short u) {
  union { unsigned int i; float f; } v; v.i = ((unsigned int)u) << 16; return v.f;
}
__device__ __forceinline__ unsigned short f2bf(float f) {
  union { float f; unsigned int i; } v; v.f = f;
  unsigned int x = v.i;
  return (unsigned short)((x + 0x7fffu + ((x >> 16) & 1u)) >> 16);
}
__device__ __forceinline__ float sigmf(float x) { return 1.f / (1.f + __expf(-x)); }

typedef float f32x4 __attribute__((ext_vector_type(4)));
typedef short short8v __attribute__((ext_vector_type(8)));
typedef short short4v __attribute__((ext_vector_type(4)));

// pack 8 f32 -> 8 bf16 (truncate)
__device__ __forceinline__ short8v pack8(const float* p) {
  union { short8v s; unsigned int u[4]; } r;
#pragma unroll
  for (int i = 0; i < 4; ++i) {
    unsigned int lo = __float_as_uint(p[2 * i]) >> 16;
    unsigned int hi = __float_as_uint(p[2 * i + 1]) & 0xFFFF0000u;
    r.u[i] = hi | lo;
  }
  return r.s;
}

#define KP 1984
#define NP 5888
#define GRU_BLOCKS 245

// ---------- prep: conv1 weight fragments (uniform K=128 map) ----------
__global__ void k_w1frag(const float* __restrict__ w1, unsigned short* __restrict__ w1f) {
  int idx = blockIdx.x * 256 + threadIdx.x;
  if (idx >= 4 * 4 * 64 * 8) return;
  int j = idx & 7, l = (idx >> 3) & 63;
  int rest = idx >> 9;  // 0..15
  int s = rest & 3, ocf = rest >> 2;
  int oc = ocf * 16 + (l & 15);
  int k = s * 32 + (l >> 4) * 8 + j;
  float v = 0.f;
  if (k < 108) {
    int fr = k / 12, fc = k - fr * 12;
    if (fc < 9) v = w1[oc * 81 + fr * 9 + fc];
  }
  w1f[idx] = f2bf(v);
}

// ---------- prep: conv2 weight fragments ----------
__global__ void k_w2frag(const float* __restrict__ w2, unsigned short* __restrict__ w2f) {
  int idx = blockIdx.x * 256 + threadIdx.x;
  if (idx >= 32 * 64 * 8) return;
  int j = idx & 7, l = (idx >> 3) & 63, s = idx >> 9;
  int oc = l & 15;
  int k = s * 32 + (l >> 4) * 8 + j;
  int t = k >> 6, ch = k & 63, fr = t >> 2, fc = t & 3;
  float v = (oc < 5) ? w2[((oc * 64 + ch) * 4 + fr) * 4 + fc] : 0.f;
  w2f[idx] = f2bf(v);
}

// ---------- prep: w_ih f32 -> bf16 [5888][1984] zero-padded ----------
__global__ void k_cvt_wih(const float* __restrict__ src, unsigned short* __restrict__ dst) {
  const int total = NP * KP / 8;
  int idx = blockIdx.x * 256 + threadIdx.x;
  if (idx >= total) return;
  int row = idx / (KP / 8);
  int c8 = (idx - row * (KP / 8)) * 8;
  short8v v = {0, 0, 0, 0, 0, 0, 0, 0};
  if (row < 5880 && c8 < 1960) {
    const float* s = src + (size_t)row * 1960 + c8;
    if (c8 + 8 <= 1960) {
      float tmp[8];
#pragma unroll
      for (int i = 0; i < 8; ++i) tmp[i] = s[i];
      v = pack8(tmp);
    } else {
      union { short8v s8; unsigned short us[8]; } u; u.s8 = v;
      for (int i = 0; i < 1960 - c8; ++i) u.us[i] = f2bf(s[i]);
      v = u.s8;
    }
  }
  *reinterpret_cast<short8v*>(dst + (size_t)idx * 8) = v;
}

// ---------- prep: zero feat_bf K-pad columns + tagged h buffers ----------
__global__ void k_featpad(unsigned short* __restrict__ feat_bf,
                          unsigned long long* __restrict__ hb0,
                          unsigned long long* __restrict__ hb1) {
  for (int i = threadIdx.x; i < 128 * 24; i += 256) {
    int n = i / 24, k = 1960 + i % 24;
    feat_bf[(size_t)n * KP + k] = 0;
  }
  for (int i = threadIdx.x; i < 3920; i += 256) {
    hb0[i] = 0ull;
    hb1[i] = 0ull;
  }
}

// ---------- kernel 1: conv1 MFMA, uniform K=128, 4-shift-copy LDS ----------
__global__ __launch_bounds__(256) void k_conv1(const float* __restrict__ x,
                                               const unsigned short* __restrict__ w1f,
                                               const float* __restrict__ b1,
                                               unsigned short* __restrict__ pool1) {
  const int n = blockIdx.x, qrg = blockIdx.y;
  const int b = n >> 5, w = n & 31;
  __shared__ __align__(16) unsigned short s_b[4 * 22 * 140];
  const int tid = threadIdx.x;
  for (int i = tid; i < 22 * 144; i += 256) {
    int lr = i / 144, lc = i - lr * 144;
    int f = 12 * qrg + lr - 2;
    int t = lc - 2;
    float v = 0.f;
    if (lr < 20 && f >= 0 && f < 257 && t >= 0 && t < 128)
      v = x[((size_t)b * 258 + 1 + f) * 2176 + w * 64 + t];
    unsigned short bf = f2bf(v);
#pragma unroll
    for (int m = 0; m < 4; ++m) {
      int d = lc + m;
      if (d < 140) s_b[m * 3080 + lr * 140 + d] = bf;
    }
  }
  const int lane = tid & 63, wv = tid >> 6;
  short8v bw[4][4];
#pragma unroll
  for (int ocf = 0; ocf < 4; ++ocf)
#pragma unroll
    for (int s = 0; s < 4; ++s)
      bw[ocf][s] = *reinterpret_cast<const short8v*>(&w1f[((ocf * 4 + s) * 64 + lane) * 8]);
  __syncthreads();

  const int li = lane & 15, g = lane >> 4;
  int fr0s[4], fc0s[4], is8s[4];
#pragma unroll
  for (int s = 0; s < 4; ++s) {
    int k0 = 32 * s + 8 * g;
    int fr = k0 / 12;
    int fc = k0 - fr * 12;
    fr0s[s] = fr; fc0s[s] = fc; is8s[s] = (fc == 8);
  }
  float bv[4];
#pragma unroll
  for (int ocf = 0; ocf < 4; ++ocf) bv[ocf] = b1[ocf * 16 + li];

  const int qr = qrg * 4 + wv;

  for (int pgt = 0; pgt < 3; ++pgt) {
    int pg = pgt * 16 + li;
    if (pg > 40) pg = 40;
    const int c0 = 3 * pg;
    int RA[3][4], RB[3][4];
#pragma unroll
    for (int phi = 0; phi < 3; ++phi) {
#pragma unroll
      for (int s = 0; s < 4; ++s) {
        int cc = c0 + phi + fc0s[s];
        int m = (-cc) & 3;
        RA[phi][s] = m * 3080 + fr0s[s] * 140 + cc + m;
        int cc2 = c0 + phi;
        int m2 = (-cc2) & 3;
        int rb8 = m2 * 3080 + (fr0s[s] + 1) * 140 + cc2 + m2;
        RB[phi][s] = is8s[s] ? rb8 : (RA[phi][s] + 4);
      }
    }
    f32x4 pm[4];
#pragma unroll
    for (int ocf = 0; ocf < 4; ++ocf) pm[ocf] = (f32x4){-3.4e38f, -3.4e38f, -3.4e38f, -3.4e38f};

    for (int rr = 0; rr < 3; ++rr) {
      const int ro = (3 * wv + rr) * 140;
#pragma unroll
      for (int phi = 0; phi < 3; ++phi) {
        f32x4 acc[4];
#pragma unroll
        for (int ocf = 0; ocf < 4; ++ocf) acc[ocf] = (f32x4){0.f, 0.f, 0.f, 0.f};
#pragma unroll
        for (int s = 0; s < 4; ++s) {
          short4v lo = *reinterpret_cast<const short4v*>(&s_b[ro + RA[phi][s]]);
          short4v hi = *reinterpret_cast<const short4v*>(&s_b[ro + RB[phi][s]]);
          short8v a = __builtin_shufflevector(lo, hi, 0, 1, 2, 3, 4, 5, 6, 7);
#pragma unroll
          for (int ocf = 0; ocf < 4; ++ocf)
            acc[ocf] = __builtin_amdgcn_mfma_f32_16x16x32_bf16(a, bw[ocf][s], acc[ocf], 0, 0, 0);
        }
#pragma unroll
        for (int ocf = 0; ocf < 4; ++ocf) {
#pragma unroll
          for (int i = 0; i < 4; ++i) pm[ocf][i] = fmaxf(pm[ocf][i], acc[ocf][i]);
        }
      }
    }
#pragma unroll
    for (int ocf = 0; ocf < 4; ++ocf) {
#pragma unroll
      for (int i = 0; i < 4; ++i) {
        int pg2 = pgt * 16 + g * 4 + i;
        if (pg2 <= 40) {
          int oc = ocf * 16 + li;
          pool1[(((size_t)n * 84 + qr) * 41 + pg2) * 64 + oc] = f2bf(sigmf(pm[ocf][i] + bv[ocf]));
        }
      }
    }
  }
}

// ---------- kernel 2: conv2 MFMA, LDS-staged A, weights in regs ----------
__global__ __launch_bounds__(128, 2) void k_conv2(const unsigned short* __restrict__ pool1,
                                                  const unsigned short* __restrict__ w2f,
                                                  const float* __restrict__ b2,
                                                  unsigned short* __restrict__ feat_bf) {
  const int n = blockIdx.x, qg = blockIdx.y;
  __shared__ __align__(16) unsigned short s_a[9 * 46 * 64];
  const int tid = threadIdx.x;
  const int lane = tid & 63, wv = tid >> 6;
  short8v bwr[32];
#pragma unroll
  for (int s = 0; s < 32; ++s)
    bwr[s] = *reinterpret_cast<const short8v*>(&w2f[(s * 64 + lane) * 8]);
  const int r0 = 6 * qg - 2;
  for (int idx = tid; idx < 9 * 46 * 8; idx += 128) {
    int row = idx / (46 * 8);
    int rem = idx - row * (46 * 8);
    int lc = rem >> 3, cp = rem & 7;
    int gr = r0 + row, gc = lc - 2;
    short8v v = {0, 0, 0, 0, 0, 0, 0, 0};
    if ((unsigned)gr < 84u && (unsigned)gc < 41u)
      v = *reinterpret_cast<const short8v*>(&pool1[(((size_t)n * 84 + gr) * 41 + gc) * 64 + cp * 8]);
    int rot = (cp * 8 + lc * 8) & 63;
    *reinterpret_cast<short8v*>(&s_a[(row * 46 + lc) * 64 + rot]) = v;
  }
  __syncthreads();

  const int q = qg * 2 + wv;
  const int li = lane & 15, g = lane >> 4;
  const int pg = li > 13 ? 13 : li;
  f32x4 pm = (f32x4){-3.4e38f, -3.4e38f, -3.4e38f, -3.4e38f};

  for (int rr = 0; rr < 3; ++rr) {
#pragma unroll
    for (int phi = 0; phi < 3; ++phi) {
      f32x4 acc[4];
#pragma unroll
      for (int i = 0; i < 4; ++i) acc[i] = (f32x4){0.f, 0.f, 0.f, 0.f};
#pragma unroll
      for (int s = 0; s < 32; ++s) {
        const int t = s >> 1, h = s & 1;
        const int fr = t >> 2, fc = t & 3;
        const int srow = 3 * wv + rr + fr;
        const int lc = 3 * pg + phi + fc;
        const int rot = (h * 32 + g * 8 + lc * 8) & 63;
        short8v a = *reinterpret_cast<const short8v*>(&s_a[(srow * 46 + lc) * 64 + rot]);
        acc[s & 3] = __builtin_amdgcn_mfma_f32_16x16x32_bf16(a, bwr[s], acc[s & 3], 0, 0, 0);
      }
      f32x4 sum;
#pragma unroll
      for (int i = 0; i < 4; ++i) sum[i] = (acc[0][i] + acc[1][i]) + (acc[2][i] + acc[3][i]);
#pragma unroll
      for (int i = 0; i < 4; ++i) pm[i] = fmaxf(pm[i], sum[i]);
    }
  }
  if (li < 5) {
#pragma unroll
    for (int i = 0; i < 4; ++i) {
      int pq = g * 4 + i;
      if (pq < 14)
        feat_bf[(size_t)n * KP + li * 392 + q * 14 + pq] = f2bf(sigmf(pm[i] + b2[li]));
    }
  }
}

// ---------- kernel 3: f32 -> bf16 convert (w_hh) ----------
__global__ void k_cvt(const float* __restrict__ src, unsigned short* __restrict__ dst, int n4) {
  for (int i = blockIdx.x * blockDim.x + threadIdx.x; i < n4; i += gridDim.x * blockDim.x) {
    float4 v = *reinterpret_cast<const float4*>(&src[i * 4]);
    ushort4 u;
    u.x = f2bf(v.x); u.y = f2bf(v.y); u.z = f2bf(v.z); u.w = f2bf(v.w);
    *reinterpret_cast<ushort4*>(&dst[i * 4]) = u;
  }
}

// ---------- kernel 4: gi MFMA GEMM ----------
__global__ __launch_bounds__(256) void k_gi(const unsigned short* __restrict__ feat_bf,
                                            const unsigned short* __restrict__ wih_bf,
                                            const float* __restrict__ b_ih,
                                            float* __restrict__ gi) {
  const int bx = blockIdx.x, bm = blockIdx.y;
  const int w = threadIdx.x >> 6, lane = threadIdx.x & 63;
  const int li = lane & 15, g = lane >> 4;
  const unsigned short* ap = feat_bf + (size_t)(bm * 64 + w * 16 + li) * KP + g * 8;
  const unsigned short* bp = wih_bf + (size_t)(bx * 16 + li) * KP + g * 8;
  f32x4 acc0 = (f32x4){0.f, 0.f, 0.f, 0.f};
  f32x4 acc1 = (f32x4){0.f, 0.f, 0.f, 0.f};
  for (int kc = 0; kc < 62; kc += 2) {
    short8v a0 = *reinterpret_cast<const short8v*>(ap + kc * 32);
    short8v b0 = *reinterpret_cast<const short8v*>(bp + kc * 32);
    short8v a1 = *reinterpret_cast<const short8v*>(ap + kc * 32 + 32);
    short8v b1 = *reinterpret_cast<const short8v*>(bp + kc * 32 + 32);
    acc0 = __builtin_amdgcn_mfma_f32_16x16x32_bf16(a0, b0, acc0, 0, 0, 0);
    acc1 = __builtin_amdgcn_mfma_f32_16x16x32_bf16(a1, b1, acc1, 0, 0, 0);
  }
  const int j = bx * 16 + li;
  if (j < 5880) {
    const float bi = b_ih[j];
    const int n0 = bm * 64 + w * 16 + g * 4;
#pragma unroll
    for (int i = 0; i < 4; ++i)
      gi[(size_t)(n0 + i) * 5880 + j] = acc0[i] + acc1[i] + bi;
  }
}

// ---------- kernel 5: persistent GRU, MFMA dot, DATA-TAGGED sync ----------
// h pair (2 k) published as u64: (tag=t+1)<<32 | bf16x2. Consumers poll the data
// word itself -> no separate flag barrier. Two buffers; the h-dependency chain
// itself prevents tag-overrun (a block needs ALL h_{t+1} before writing t+2).
__global__ __launch_bounds__(256) void k_gru(const unsigned short* __restrict__ whh,
                                             const float* __restrict__ b_hh,
                                             const float* __restrict__ gi,
                                             const float* __restrict__ hx0,
                                             unsigned long long* __restrict__ hb0,
                                             unsigned long long* __restrict__ hb1) {
  __shared__ __align__(16) unsigned short s_w[2 * 62 * 64 * 8];  // 126976 B
  __shared__ __align__(16) unsigned short s_h[4 * 1984];         // 15872 B
  __shared__ float s_part[4 * 2 * 64 * 4];                        // 8192 B
  __shared__ float s_gh[96];
  __shared__ float s_gi[96];
  const int tid = threadIdx.x;
  const int bid = blockIdx.x;
  const int k0 = bid * 8;
  const int lane = tid & 63, wv = tid >> 6;
  const int li = lane & 15, g2 = lane >> 4;

  // preload w A-fragments
  for (int idx = tid; idx < 2 * 62 * 64; idx += 256) {
    int mt = idx / 3968;
    int rem = idx - mt * 3968;
    int kc = rem >> 6, l = rem & 63;
    int lli = l & 15, lg2 = l >> 4;
    int k = kc * 32 + lg2 * 8;
    short8v v = {0, 0, 0, 0, 0, 0, 0, 0};
    bool rowok = (mt == 0) ? true : (lli < 8);
    if (rowok && k < 1960) {
      int g = (mt == 0) ? (lli >> 3) : 2;
      int kk = (mt == 0) ? (lli & 7) : lli;
      v = *reinterpret_cast<const short8v*>(&whh[(size_t)(g * 1960 + k0 + kk) * 1960 + k]);
    }
    *reinterpret_cast<short8v*>(&s_w[(size_t)idx * 8]) = v;
  }
  // zero s_h (K-pad region stays zero)
  for (int i = tid; i < 4 * 992; i += 256) reinterpret_cast<unsigned int*>(s_h)[i] = 0u;

  // update-thread state: tid<16 -> (cb = tid>>2, pair p = tid&3), k = k0+2p, k0+2p+1
  float hp0 = 0.f, hp1 = 0.f, bhr0 = 0, bhr1 = 0, bhz0 = 0, bhz1 = 0, bhn0 = 0, bhn1 = 0;
  if (tid < 16) {
    int cb = tid >> 2, p = tid & 3;
    int k = k0 + 2 * p;
    hp0 = hx0[cb * 1960 + k];
    hp1 = hx0[cb * 1960 + k + 1];
    bhr0 = b_hh[k];         bhr1 = b_hh[k + 1];
    bhz0 = b_hh[1960 + k];  bhz1 = b_hh[1960 + k + 1];
    bhn0 = b_hh[3920 + k];  bhn1 = b_hh[3920 + k + 1];
  }
  __syncthreads();

  for (int t = 0; t < 32; ++t) {
    // ---- stage h into LDS (poll tagged data for t>=1) + prefetch gi ----
    if (t == 0) {
      for (int i = tid; i < 7840; i += 256) {
        int b = i / 1960, k = i - b * 1960;
        s_h[b * 1984 + k] = f2bf(hx0[i]);
      }
    } else {
      const unsigned long long* hin = (t & 1) ? hb1 : hb0;  // h_t lives in hb[t&1]
      unsigned long long v[16];
#pragma unroll
      for (int r = 0; r < 16; ++r) {
        int i = tid + (r << 8);
        v[r] = (i < 3920)
                   ? __hip_atomic_load(&hin[i], __ATOMIC_RELAXED, __HIP_MEMORY_SCOPE_AGENT)
                   : 0ull;
      }
#pragma unroll
      for (int r = 0; r < 16; ++r) {
        int i = tid + (r << 8);
        if (i < 3920) {
          while ((unsigned)(v[r] >> 32) < (unsigned)t) {
            __builtin_amdgcn_s_sleep(0);
            v[r] = __hip_atomic_load(&hin[i], __ATOMIC_RELAXED, __HIP_MEMORY_SCOPE_AGENT);
          }
          int b = i / 980, kp = i - b * 980;
          reinterpret_cast<unsigned int*>(s_h)[b * 992 + kp] = (unsigned)v[r];
        }
      }
    }
    if (tid < 96) {
      int gg = tid >> 5, bb = (tid >> 3) & 3, kk = tid & 7;
      s_gi[tid] = gi[(size_t)(bb * 32 + t) * 5880 + gg * 1960 + k0 + kk];
    }
    __syncthreads();

    // ---- MFMA dot: wave wv handles kc = wv, wv+4, ... ----
    f32x4 acc0 = (f32x4){0.f, 0.f, 0.f, 0.f};
    f32x4 acc1 = (f32x4){0.f, 0.f, 0.f, 0.f};
    for (int kc = wv; kc < 62; kc += 4) {
      short8v bfr = *reinterpret_cast<const short8v*>(&s_h[(li & 3) * 1984 + kc * 32 + g2 * 8]);
      short8v a0 = *reinterpret_cast<const short8v*>(&s_w[((size_t)kc * 64 + lane) * 8]);
      short8v a1 = *reinterpret_cast<const short8v*>(&s_w[((size_t)(62 + kc) * 64 + lane) * 8]);
      acc0 = __builtin_amdgcn_mfma_f32_16x16x32_bf16(a0, bfr, acc0, 0, 0, 0);
      acc1 = __builtin_amdgcn_mfma_f32_16x16x32_bf16(a1, bfr, acc1, 0, 0, 0);
    }
    *reinterpret_cast<f32x4*>(&s_part[((wv * 2 + 0) * 64 + lane) * 4]) = acc0;
    *reinterpret_cast<f32x4*>(&s_part[((wv * 2 + 1) * 64 + lane) * 4]) = acc1;
    __syncthreads();

    // ---- reduce 4 waves -> s_gh[g*32 + b*8 + kk] ----
    if (tid < 128) {
      int mt = tid >> 6, l2 = tid & 63;
      int n = l2 & 15, rb = (l2 >> 4) * 4;
      if (n < 4) {
#pragma unroll
        for (int i = 0; i < 4; ++i) {
          int m = rb + i;
          bool ok = (mt == 0) ? true : (m < 8);
          if (ok) {
            float s = s_part[((0 * 2 + mt) * 64 + l2) * 4 + i] +
                      s_part[((1 * 2 + mt) * 64 + l2) * 4 + i] +
                      s_part[((2 * 2 + mt) * 64 + l2) * 4 + i] +
                      s_part[((3 * 2 + mt) * 64 + l2) * 4 + i];
            int g = (mt == 0) ? (m >> 3) : 2;
            int kk = (mt == 0) ? (m & 7) : m;
            s_gh[g * 32 + n * 8 + kk] = s;
          }
        }
      }
    }
    __syncthreads();

    // ---- update + tagged publish ----
    unsigned long long* hout = (t & 1) ? hb0 : hb1;  // h_{t+1} -> hb[(t+1)&1]
    if (tid < 16) {
      int cb = tid >> 2, p = tid & 3;
      int kk = 2 * p;
      float r0 = sigmf(s_gi[cb * 8 + kk] + s_gh[cb * 8 + kk] + bhr0);
      float z0 = sigmf(s_gi[32 + cb * 8 + kk] + s_gh[32 + cb * 8 + kk] + bhz0);
      float n0 = tanhf(s_gi[64 + cb * 8 + kk] + r0 * (s_gh[64 + cb * 8 + kk] + bhn0));
      float h0v = (1.f - z0) * n0 + z0 * hp0;
      float r1 = sigmf(s_gi[cb * 8 + kk + 1] + s_gh[cb * 8 + kk + 1] + bhr1);
      float z1 = sigmf(s_gi[32 + cb * 8 + kk + 1] + s_gh[32 + cb * 8 + kk + 1] + bhz1);
      float n1 = tanhf(s_gi[64 + cb * 8 + kk + 1] + r1 * (s_gh[64 + cb * 8 + kk + 1] + bhn1));
      float h1v = (1.f - z1) * n1 + z1 * hp1;
      hp0 = h0v; hp1 = h1v;
      unsigned long long packed =
          ((unsigned long long)(unsigned)(t + 1) << 32) |
          (unsigned long long)((unsigned)f2bf(h0v) | ((unsigned)f2bf(h1v) << 16));
      __hip_atomic_store(&hout[cb * 980 + (k0 >> 1) + p], packed,
                         __ATOMIC_RELAXED, __HIP_MEMORY_SCOPE_AGENT);
    }
    __syncthreads();  // protect s_h/s_gi/s_gh reuse next iteration
  }
}

// ---------- kernel 6: fc + softmax + labels (tagged-u64 h) ----------
__global__ void k_fc(const unsigned long long* __restrict__ h, const float* __restrict__ fc_w,
                     const float* __restrict__ fc_b, const int* __restrict__ labels,
                     float* __restrict__ out) {
  const int l = threadIdx.x;
  float acc[8];
#pragma unroll
  for (int i = 0; i < 8; ++i) acc[i] = 0.f;
  for (int p = l; p < 980; p += 64) {
    const float w0a = fc_w[2 * p], w0b = fc_w[2 * p + 1];
    const float w1a = fc_w[1960 + 2 * p], w1b = fc_w[1960 + 2 * p + 1];
#pragma unroll
    for (int b = 0; b < 4; ++b) {
      unsigned int d = (unsigned int)h[b * 980 + p];
      float ha = bf2f((unsigned short)(d & 0xffff));
      float hb = bf2f((unsigned short)(d >> 16));
      acc[b * 2 + 0] += ha * w0a + hb * w0b;
      acc[b * 2 + 1] += ha * w1a + hb * w1b;
    }
  }
#pragma unroll
  for (int i = 0; i < 8; ++i) {
    float a = acc[i];
#pragma unroll
    for (int off = 32; off; off >>= 1) a += __shfl_xor(a, off, 64);
    acc[i] = a;
  }
  if (l == 0) {
#pragma unroll
    for (int b = 0; b < 4; ++b) {
      const float l0 = acc[b * 2] + fc_b[0], l1 = acc[b * 2 + 1] + fc_b[1];
      const float m = fmaxf(l0, l1);
      const float e0 = __expf(l0 - m), e1 = __expf(l1 - m);
      const float s = e0 + e1;
      out[b * 2 + 0] = e0 / s;
      out[b * 2 + 1] = e1 / s;
    }
    for (int i = 0; i < 4; ++i) out[8 + i] = (float)labels[i];
  }
}

extern "C" void kernel_launch(void* const* d_in, const int* in_sizes, int n_in,
                              void* d_out, int out_size, void* d_ws, size_t ws_size,
                              hipStream_t stream) {
  const float* x       = (const float*)d_in[0];
  const float* hx0     = (const float*)d_in[1];
  const int*   labels  = (const int*)d_in[2];
  const float* conv1_w = (const float*)d_in[3];
  const float* conv1_b = (const float*)d_in[4];
  const float* conv2_w = (const float*)d_in[5];
  const float* conv2_b = (const float*)d_in[6];
  const float* w_ih    = (const float*)d_in[7];
  const float* w_hh    = (const float*)d_in[8];
  const float* b_ih    = (const float*)d_in[9];
  const float* b_hh    = (const float*)d_in[10];
  const float* fc_w    = (const float*)d_in[11];
  const float* fc_b    = (const float*)d_in[12];

  char* ws = (char*)d_ws;
  size_t off = 0;
  unsigned short* pool1 = (unsigned short*)(ws + off); off += (size_t)128 * 84 * 41 * 64 * 2;  // 56.4MB
  unsigned short* feat_bf = (unsigned short*)(ws + off); off += (size_t)128 * KP * 2;          // 0.5MB
  float* gi    = (float*)(ws + off); off += (size_t)128 * 5880 * 4;                            // 3.0MB
  unsigned short* whh_bf = (unsigned short*)(ws + off); off += (size_t)5880 * 1960 * 2;        // 23.0MB
  unsigned short* wih_bf = (unsigned short*)(ws + off); off += (size_t)NP * KP * 2;            // 23.4MB
  unsigned long long* hb0 = (unsigned long long*)(ws + off); off += (size_t)4 * 980 * 8;       // 31.4KB
  unsigned long long* hb1 = (unsigned long long*)(ws + off); off += (size_t)4 * 980 * 8;       // 31.4KB
  unsigned short* w1f = (unsigned short*)(ws + off); off += (size_t)4 * 4 * 64 * 8 * 2;        // 16KB
  unsigned short* w2f = (unsigned short*)(ws + off); off += (size_t)32 * 64 * 8 * 2;           // 32KB

  k_cvt<<<2048, 256, 0, stream>>>(w_hh, whh_bf, 5880 * 1960 / 4);
  k_cvt_wih<<<(NP * KP / 8 + 255) / 256, 256, 0, stream>>>(w_ih, wih_bf);
  k_w1frag<<<32, 256, 0, stream>>>(conv1_w, w1f);
  k_w2frag<<<64, 256, 0, stream>>>(conv2_w, w2f);
  k_featpad<<<1, 256, 0, stream>>>(feat_bf, hb0, hb1);

  dim3 g1(128, 21);
  k_conv1<<<g1, 256, 0, stream>>>(x, w1f, conv1_b, pool1);

  dim3 g2(128, 14);
  k_conv2<<<g2, 128, 0, stream>>>(pool1, w2f, conv2_b, feat_bf);

  dim3 g3(368, 2);
  k_gi<<<g3, 256, 0, stream>>>(feat_bf, wih_bf, b_ih, gi);

  // all 32 GRU steps, persistent MFMA, data-tagged sync; final h_32 in hb0
  void* gru_args[] = {(void*)&whh_bf, (void*)&b_hh, (void*)&gi, (void*)&hx0,
                      (void*)&hb0, (void*)&hb1};
  hipLaunchCooperativeKernel((const void*)k_gru, dim3(GRU_BLOCKS), dim3(256), gru_args, 0, stream);

  k_fc<<<1, 64, 0, stream>>>(hb0, fc_w, fc_b, labels, (float*)d_out);
}

// Round 10
// 474.765 us; speedup vs baseline: 3.3693x; 1.1919x over previous
//
#include <hip/hip_runtime.h>
#include <hip/hip_cooperative_groups.h>

// ---------- helpers ----------
__device__ __forceinline__ float bf2f(unsigned short u) {
  union { unsigned int i; float f; } v; v.i = ((unsigned int)u) << 16; return v.f;
}
__device__ __forceinline__ unsigned short f2bf(float f) {
  union { float f; unsigned int i; } v; v.f = f;
  unsigned int x = v.i;
  return (unsigned short)((x + 0x7fffu + ((x >> 16) & 1u)) >> 16);
}
__device__ __forceinline__ float sigmf(float x) { return 1.f / (1.f + __expf(-x)); }

typedef float f32x4 __attribute__((ext_vector_type(4)));
typedef short short8v __attribute__((ext_vector_type(8)));
typedef short short4v __attribute__((ext_vector_type(4)));

// pack 8 f32 -> 8 bf16 (truncate)
__device__ __forceinline__ short8v pack8(const float* p) {
  union { short8v s; unsigned int u[4]; } r;
#pragma unroll
  for (int i = 0; i < 4; ++i) {
    unsigned int lo = __float_as_uint(p[2 * i]) >> 16;
    unsigned int hi = __float_as_uint(p[2 * i + 1]) & 0xFFFF0000u;
    r.u[i] = hi | lo;
  }
  return r.s;
}

#define KP 1984
#define NP 5888
#define GRU_BLOCKS 245

// ---------- prep: conv1 weight fragments (uniform K=128 map) ----------
__global__ void k_w1frag(const float* __restrict__ w1, unsigned short* __restrict__ w1f) {
  int idx = blockIdx.x * 256 + threadIdx.x;
  if (idx >= 4 * 4 * 64 * 8) return;
  int j = idx & 7, l = (idx >> 3) & 63;
  int rest = idx >> 9;  // 0..15
  int s = rest & 3, ocf = rest >> 2;
  int oc = ocf * 16 + (l & 15);
  int k = s * 32 + (l >> 4) * 8 + j;
  float v = 0.f;
  if (k < 108) {
    int fr = k / 12, fc = k - fr * 12;
    if (fc < 9) v = w1[oc * 81 + fr * 9 + fc];
  }
  w1f[idx] = f2bf(v);
}

// ---------- prep: conv2 weight fragments ----------
__global__ void k_w2frag(const float* __restrict__ w2, unsigned short* __restrict__ w2f) {
  int idx = blockIdx.x * 256 + threadIdx.x;
  if (idx >= 32 * 64 * 8) return;
  int j = idx & 7, l = (idx >> 3) & 63, s = idx >> 9;
  int oc = l & 15;
  int k = s * 32 + (l >> 4) * 8 + j;
  int t = k >> 6, ch = k & 63, fr = t >> 2, fc = t & 3;
  float v = (oc < 5) ? w2[((oc * 64 + ch) * 4 + fr) * 4 + fc] : 0.f;
  w2f[idx] = f2bf(v);
}

// ---------- prep: w_ih f32 -> bf16 [5888][1984] zero-padded ----------
__global__ void k_cvt_wih(const float* __restrict__ src, unsigned short* __restrict__ dst) {
  const int total = NP * KP / 8;
  int idx = blockIdx.x * 256 + threadIdx.x;
  if (idx >= total) return;
  int row = idx / (KP / 8);
  int c8 = (idx - row * (KP / 8)) * 8;
  short8v v = {0, 0, 0, 0, 0, 0, 0, 0};
  if (row < 5880 && c8 < 1960) {
    const float* s = src + (size_t)row * 1960 + c8;
    if (c8 + 8 <= 1960) {
      float tmp[8];
#pragma unroll
      for (int i = 0; i < 8; ++i) tmp[i] = s[i];
      v = pack8(tmp);
    } else {
      union { short8v s8; unsigned short us[8]; } u; u.s8 = v;
      for (int i = 0; i < 1960 - c8; ++i) u.us[i] = f2bf(s[i]);
      v = u.s8;
    }
  }
  *reinterpret_cast<short8v*>(dst + (size_t)idx * 8) = v;
}

// ---------- prep: zero feat_bf K-pad columns + tagged h buffers ----------
__global__ void k_featpad(unsigned short* __restrict__ feat_bf,
                          unsigned long long* __restrict__ hb0,
                          unsigned long long* __restrict__ hb1) {
  for (int i = threadIdx.x; i < 128 * 24; i += 256) {
    int n = i / 24, k = 1960 + i % 24;
    feat_bf[(size_t)n * KP + k] = 0;
  }
  for (int i = threadIdx.x; i < 3920; i += 256) {
    hb0[i] = 0ull;
    hb1[i] = 0ull;
  }
}

// ---------- kernel 1: conv1 MFMA, uniform K=128, 4-shift-copy LDS ----------
__global__ __launch_bounds__(256) void k_conv1(const float* __restrict__ x,
                                               const unsigned short* __restrict__ w1f,
                                               const float* __restrict__ b1,
                                               unsigned short* __restrict__ pool1) {
  const int n = blockIdx.x, qrg = blockIdx.y;
  const int b = n >> 5, w = n & 31;
  __shared__ __align__(16) unsigned short s_b[4 * 22 * 140];
  const int tid = threadIdx.x;
  for (int i = tid; i < 22 * 144; i += 256) {
    int lr = i / 144, lc = i - lr * 144;
    int f = 12 * qrg + lr - 2;
    int t = lc - 2;
    float v = 0.f;
    if (lr < 20 && f >= 0 && f < 257 && t >= 0 && t < 128)
      v = x[((size_t)b * 258 + 1 + f) * 2176 + w * 64 + t];
    unsigned short bf = f2bf(v);
#pragma unroll
    for (int m = 0; m < 4; ++m) {
      int d = lc + m;
      if (d < 140) s_b[m * 3080 + lr * 140 + d] = bf;
    }
  }
  const int lane = tid & 63, wv = tid >> 6;
  short8v bw[4][4];
#pragma unroll
  for (int ocf = 0; ocf < 4; ++ocf)
#pragma unroll
    for (int s = 0; s < 4; ++s)
      bw[ocf][s] = *reinterpret_cast<const short8v*>(&w1f[((ocf * 4 + s) * 64 + lane) * 8]);
  __syncthreads();

  const int li = lane & 15, g = lane >> 4;
  int fr0s[4], fc0s[4], is8s[4];
#pragma unroll
  for (int s = 0; s < 4; ++s) {
    int k0 = 32 * s + 8 * g;
    int fr = k0 / 12;
    int fc = k0 - fr * 12;
    fr0s[s] = fr; fc0s[s] = fc; is8s[s] = (fc == 8);
  }
  float bv[4];
#pragma unroll
  for (int ocf = 0; ocf < 4; ++ocf) bv[ocf] = b1[ocf * 16 + li];

  const int qr = qrg * 4 + wv;

  for (int pgt = 0; pgt < 3; ++pgt) {
    int pg = pgt * 16 + li;
    if (pg > 40) pg = 40;
    const int c0 = 3 * pg;
    int RA[3][4], RB[3][4];
#pragma unroll
    for (int phi = 0; phi < 3; ++phi) {
#pragma unroll
      for (int s = 0; s < 4; ++s) {
        int cc = c0 + phi + fc0s[s];
        int m = (-cc) & 3;
        RA[phi][s] = m * 3080 + fr0s[s] * 140 + cc + m;
        int cc2 = c0 + phi;
        int m2 = (-cc2) & 3;
        int rb8 = m2 * 3080 + (fr0s[s] + 1) * 140 + cc2 + m2;
        RB[phi][s] = is8s[s] ? rb8 : (RA[phi][s] + 4);
      }
    }
    f32x4 pm[4];
#pragma unroll
    for (int ocf = 0; ocf < 4; ++ocf) pm[ocf] = (f32x4){-3.4e38f, -3.4e38f, -3.4e38f, -3.4e38f};

    for (int rr = 0; rr < 3; ++rr) {
      const int ro = (3 * wv + rr) * 140;
#pragma unroll
      for (int phi = 0; phi < 3; ++phi) {
        f32x4 acc[4];
#pragma unroll
        for (int ocf = 0; ocf < 4; ++ocf) acc[ocf] = (f32x4){0.f, 0.f, 0.f, 0.f};
#pragma unroll
        for (int s = 0; s < 4; ++s) {
          short4v lo = *reinterpret_cast<const short4v*>(&s_b[ro + RA[phi][s]]);
          short4v hi = *reinterpret_cast<const short4v*>(&s_b[ro + RB[phi][s]]);
          short8v a = __builtin_shufflevector(lo, hi, 0, 1, 2, 3, 4, 5, 6, 7);
#pragma unroll
          for (int ocf = 0; ocf < 4; ++ocf)
            acc[ocf] = __builtin_amdgcn_mfma_f32_16x16x32_bf16(a, bw[ocf][s], acc[ocf], 0, 0, 0);
        }
#pragma unroll
        for (int ocf = 0; ocf < 4; ++ocf) {
#pragma unroll
          for (int i = 0; i < 4; ++i) pm[ocf][i] = fmaxf(pm[ocf][i], acc[ocf][i]);
        }
      }
    }
#pragma unroll
    for (int ocf = 0; ocf < 4; ++ocf) {
#pragma unroll
      for (int i = 0; i < 4; ++i) {
        int pg2 = pgt * 16 + g * 4 + i;
        if (pg2 <= 40) {
          int oc = ocf * 16 + li;
          pool1[(((size_t)n * 84 + qr) * 41 + pg2) * 64 + oc] = f2bf(sigmf(pm[ocf][i] + bv[ocf]));
        }
      }
    }
  }
}

// ---------- kernel 2: conv2 MFMA, LDS-staged A, weights in regs ----------
__global__ __launch_bounds__(128, 2) void k_conv2(const unsigned short* __restrict__ pool1,
                                                  const unsigned short* __restrict__ w2f,
                                                  const float* __restrict__ b2,
                                                  unsigned short* __restrict__ feat_bf) {
  const int n = blockIdx.x, qg = blockIdx.y;
  __shared__ __align__(16) unsigned short s_a[9 * 46 * 64];
  const int tid = threadIdx.x;
  const int lane = tid & 63, wv = tid >> 6;
  short8v bwr[32];
#pragma unroll
  for (int s = 0; s < 32; ++s)
    bwr[s] = *reinterpret_cast<const short8v*>(&w2f[(s * 64 + lane) * 8]);
  const int r0 = 6 * qg - 2;
  for (int idx = tid; idx < 9 * 46 * 8; idx += 128) {
    int row = idx / (46 * 8);
    int rem = idx - row * (46 * 8);
    int lc = rem >> 3, cp = rem & 7;
    int gr = r0 + row, gc = lc - 2;
    short8v v = {0, 0, 0, 0, 0, 0, 0, 0};
    if ((unsigned)gr < 84u && (unsigned)gc < 41u)
      v = *reinterpret_cast<const short8v*>(&pool1[(((size_t)n * 84 + gr) * 41 + gc) * 64 + cp * 8]);
    int rot = (cp * 8 + lc * 8) & 63;
    *reinterpret_cast<short8v*>(&s_a[(row * 46 + lc) * 64 + rot]) = v;
  }
  __syncthreads();

  const int q = qg * 2 + wv;
  const int li = lane & 15, g = lane >> 4;
  const int pg = li > 13 ? 13 : li;
  f32x4 pm = (f32x4){-3.4e38f, -3.4e38f, -3.4e38f, -3.4e38f};

  for (int rr = 0; rr < 3; ++rr) {
#pragma unroll
    for (int phi = 0; phi < 3; ++phi) {
      f32x4 acc[4];
#pragma unroll
      for (int i = 0; i < 4; ++i) acc[i] = (f32x4){0.f, 0.f, 0.f, 0.f};
#pragma unroll
      for (int s = 0; s < 32; ++s) {
        const int t = s >> 1, h = s & 1;
        const int fr = t >> 2, fc = t & 3;
        const int srow = 3 * wv + rr + fr;
        const int lc = 3 * pg + phi + fc;
        const int rot = (h * 32 + g * 8 + lc * 8) & 63;
        short8v a = *reinterpret_cast<const short8v*>(&s_a[(srow * 46 + lc) * 64 + rot]);
        acc[s & 3] = __builtin_amdgcn_mfma_f32_16x16x32_bf16(a, bwr[s], acc[s & 3], 0, 0, 0);
      }
      f32x4 sum;
#pragma unroll
      for (int i = 0; i < 4; ++i) sum[i] = (acc[0][i] + acc[1][i]) + (acc[2][i] + acc[3][i]);
#pragma unroll
      for (int i = 0; i < 4; ++i) pm[i] = fmaxf(pm[i], sum[i]);
    }
  }
  if (li < 5) {
#pragma unroll
    for (int i = 0; i < 4; ++i) {
      int pq = g * 4 + i;
      if (pq < 14)
        feat_bf[(size_t)n * KP + li * 392 + q * 14 + pq] = f2bf(sigmf(pm[i] + b2[li]));
    }
  }
}

// ---------- kernel 3: f32 -> bf16 convert (w_hh) ----------
__global__ void k_cvt(const float* __restrict__ src, unsigned short* __restrict__ dst, int n4) {
  for (int i = blockIdx.x * blockDim.x + threadIdx.x; i < n4; i += gridDim.x * blockDim.x) {
    float4 v = *reinterpret_cast<const float4*>(&src[i * 4]);
    ushort4 u;
    u.x = f2bf(v.x); u.y = f2bf(v.y); u.z = f2bf(v.z); u.w = f2bf(v.w);
    *reinterpret_cast<ushort4*>(&dst[i * 4]) = u;
  }
}

// ---------- kernel 4: gi MFMA GEMM ----------
__global__ __launch_bounds__(256) void k_gi(const unsigned short* __restrict__ feat_bf,
                                            const unsigned short* __restrict__ wih_bf,
                                            const float* __restrict__ b_ih,
                                            float* __restrict__ gi) {
  const int bx = blockIdx.x, bm = blockIdx.y;
  const int w = threadIdx.x >> 6, lane = threadIdx.x & 63;
  const int li = lane & 15, g = lane >> 4;
  const unsigned short* ap = feat_bf + (size_t)(bm * 64 + w * 16 + li) * KP + g * 8;
  const unsigned short* bp = wih_bf + (size_t)(bx * 16 + li) * KP + g * 8;
  f32x4 acc0 = (f32x4){0.f, 0.f, 0.f, 0.f};
  f32x4 acc1 = (f32x4){0.f, 0.f, 0.f, 0.f};
  for (int kc = 0; kc < 62; kc += 2) {
    short8v a0 = *reinterpret_cast<const short8v*>(ap + kc * 32);
    short8v b0 = *reinterpret_cast<const short8v*>(bp + kc * 32);
    short8v a1 = *reinterpret_cast<const short8v*>(ap + kc * 32 + 32);
    short8v b1 = *reinterpret_cast<const short8v*>(bp + kc * 32 + 32);
    acc0 = __builtin_amdgcn_mfma_f32_16x16x32_bf16(a0, b0, acc0, 0, 0, 0);
    acc1 = __builtin_amdgcn_mfma_f32_16x16x32_bf16(a1, b1, acc1, 0, 0, 0);
  }
  const int j = bx * 16 + li;
  if (j < 5880) {
    const float bi = b_ih[j];
    const int n0 = bm * 64 + w * 16 + g * 4;
#pragma unroll
    for (int i = 0; i < 4; ++i)
      gi[(size_t)(n0 + i) * 5880 + j] = acc0[i] + acc1[i] + bi;
  }
}

// ---------- kernel 5: persistent GRU, MFMA dot, data-tagged sync, batched re-poll ----------
// 512 threads (8 waves): waves 0-3 run the MFMA dot; all 8 stage/poll.
// h pair published as u64: (tag=t+1)<<32 | bf16x2; consumers poll the data words
// themselves with a pending-bitmask loop (all pending loads re-issued per round,
// pipelined -> one LLC round trip per poll round, not a serial chain).
__global__ __launch_bounds__(512) void k_gru(const unsigned short* __restrict__ whh,
                                             const float* __restrict__ b_hh,
                                             const float* __restrict__ gi,
                                             const float* __restrict__ hx0,
                                             unsigned long long* __restrict__ hb0,
                                             unsigned long long* __restrict__ hb1) {
  __shared__ __align__(16) unsigned short s_w[2 * 62 * 64 * 8];  // 126976 B
  __shared__ __align__(16) unsigned short s_h[4 * 1984];         // 15872 B
  __shared__ float s_part[4 * 2 * 64 * 4];                        // 8192 B
  __shared__ float s_gh[96];
  __shared__ float s_gi[96];
  const int tid = threadIdx.x;
  const int bid = blockIdx.x;
  const int k0 = bid * 8;
  const int lane = tid & 63, wv = tid >> 6;
  const int li = lane & 15, g2 = lane >> 4;

  // preload w A-fragments
  for (int idx = tid; idx < 2 * 62 * 64; idx += 512) {
    int mt = idx / 3968;
    int rem = idx - mt * 3968;
    int kc = rem >> 6, l = rem & 63;
    int lli = l & 15, lg2 = l >> 4;
    int k = kc * 32 + lg2 * 8;
    short8v v = {0, 0, 0, 0, 0, 0, 0, 0};
    bool rowok = (mt == 0) ? true : (lli < 8);
    if (rowok && k < 1960) {
      int g = (mt == 0) ? (lli >> 3) : 2;
      int kk = (mt == 0) ? (lli & 7) : lli;
      v = *reinterpret_cast<const short8v*>(&whh[(size_t)(g * 1960 + k0 + kk) * 1960 + k]);
    }
    *reinterpret_cast<short8v*>(&s_w[(size_t)idx * 8]) = v;
  }
  // zero s_h (K-pad region stays zero)
  for (int i = tid; i < 4 * 992; i += 512) reinterpret_cast<unsigned int*>(s_h)[i] = 0u;

  // update-thread state: tid<16 -> (cb = tid>>2, pair p = tid&3), k = k0+2p, k0+2p+1
  float hp0 = 0.f, hp1 = 0.f, bhr0 = 0, bhr1 = 0, bhz0 = 0, bhz1 = 0, bhn0 = 0, bhn1 = 0;
  if (tid < 16) {
    int cb = tid >> 2, p = tid & 3;
    int k = k0 + 2 * p;
    hp0 = hx0[cb * 1960 + k];
    hp1 = hx0[cb * 1960 + k + 1];
    bhr0 = b_hh[k];         bhr1 = b_hh[k + 1];
    bhz0 = b_hh[1960 + k];  bhz1 = b_hh[1960 + k + 1];
    bhn0 = b_hh[3920 + k];  bhn1 = b_hh[3920 + k + 1];
  }
  __syncthreads();

  for (int t = 0; t < 32; ++t) {
    // ---- stage h into LDS (batched tagged poll for t>=1) + prefetch gi ----
    if (t == 0) {
      for (int i = tid; i < 7840; i += 512) {
        int b = i / 1960, k = i - b * 1960;
        s_h[b * 1984 + k] = f2bf(hx0[i]);
      }
    } else {
      const unsigned long long* hin = (t & 1) ? hb1 : hb0;  // h_t lives in hb[t&1]
      unsigned pend = 0;
#pragma unroll
      for (int r = 0; r < 8; ++r)
        if (tid + (r << 9) < 3920) pend |= (1u << r);
      while (pend) {
        unsigned long long v[8];
#pragma unroll
        for (int r = 0; r < 8; ++r)
          if (pend & (1u << r))
            v[r] = __hip_atomic_load(&hin[tid + (r << 9)], __ATOMIC_RELAXED,
                                     __HIP_MEMORY_SCOPE_AGENT);
#pragma unroll
        for (int r = 0; r < 8; ++r) {
          if ((pend & (1u << r)) && (unsigned)(v[r] >> 32) >= (unsigned)t) {
            int i = tid + (r << 9);
            int b = i / 980, kp = i - b * 980;
            reinterpret_cast<unsigned int*>(s_h)[b * 992 + kp] = (unsigned)v[r];
            pend &= ~(1u << r);
          }
        }
        if (pend) __builtin_amdgcn_s_sleep(0);
      }
    }
    if (tid < 96) {
      int gg = tid >> 5, bb = (tid >> 3) & 3, kk = tid & 7;
      s_gi[tid] = gi[(size_t)(bb * 32 + t) * 5880 + gg * 1960 + k0 + kk];
    }
    __syncthreads();

    // ---- MFMA dot (waves 0-3): wave wv handles kc = wv, wv+4, ... ----
    if (wv < 4) {
      f32x4 acc0 = (f32x4){0.f, 0.f, 0.f, 0.f};
      f32x4 acc1 = (f32x4){0.f, 0.f, 0.f, 0.f};
      for (int kc = wv; kc < 62; kc += 4) {
        short8v bfr = *reinterpret_cast<const short8v*>(&s_h[(li & 3) * 1984 + kc * 32 + g2 * 8]);
        short8v a0 = *reinterpret_cast<const short8v*>(&s_w[((size_t)kc * 64 + lane) * 8]);
        short8v a1 = *reinterpret_cast<const short8v*>(&s_w[((size_t)(62 + kc) * 64 + lane) * 8]);
        acc0 = __builtin_amdgcn_mfma_f32_16x16x32_bf16(a0, bfr, acc0, 0, 0, 0);
        acc1 = __builtin_amdgcn_mfma_f32_16x16x32_bf16(a1, bfr, acc1, 0, 0, 0);
      }
      *reinterpret_cast<f32x4*>(&s_part[((wv * 2 + 0) * 64 + lane) * 4]) = acc0;
      *reinterpret_cast<f32x4*>(&s_part[((wv * 2 + 1) * 64 + lane) * 4]) = acc1;
    }
    __syncthreads();

    // ---- reduce 4 waves -> s_gh[g*32 + b*8 + kk] ----
    if (tid < 128) {
      int mt = tid >> 6, l2 = tid & 63;
      int n = l2 & 15, rb = (l2 >> 4) * 4;
      if (n < 4) {
#pragma unroll
        for (int i = 0; i < 4; ++i) {
          int m = rb + i;
          bool ok = (mt == 0) ? true : (m < 8);
          if (ok) {
            float s = s_part[((0 * 2 + mt) * 64 + l2) * 4 + i] +
                      s_part[((1 * 2 + mt) * 64 + l2) * 4 + i] +
                      s_part[((2 * 2 + mt) * 64 + l2) * 4 + i] +
                      s_part[((3 * 2 + mt) * 64 + l2) * 4 + i];
            int g = (mt == 0) ? (m >> 3) : 2;
            int kk = (mt == 0) ? (m & 7) : m;
            s_gh[g * 32 + n * 8 + kk] = s;
          }
        }
      }
    }
    __syncthreads();

    // ---- update + tagged publish ----
    unsigned long long* hout = (t & 1) ? hb0 : hb1;  // h_{t+1} -> hb[(t+1)&1]
    if (tid < 16) {
      int cb = tid >> 2, p = tid & 3;
      int kk = 2 * p;
      float r0 = sigmf(s_gi[cb * 8 + kk] + s_gh[cb * 8 + kk] + bhr0);
      float z0 = sigmf(s_gi[32 + cb * 8 + kk] + s_gh[32 + cb * 8 + kk] + bhz0);
      float n0 = tanhf(s_gi[64 + cb * 8 + kk] + r0 * (s_gh[64 + cb * 8 + kk] + bhn0));
      float h0v = (1.f - z0) * n0 + z0 * hp0;
      float r1 = sigmf(s_gi[cb * 8 + kk + 1] + s_gh[cb * 8 + kk + 1] + bhr1);
      float z1 = sigmf(s_gi[32 + cb * 8 + kk + 1] + s_gh[32 + cb * 8 + kk + 1] + bhz1);
      float n1 = tanhf(s_gi[64 + cb * 8 + kk + 1] + r1 * (s_gh[64 + cb * 8 + kk + 1] + bhn1));
      float h1v = (1.f - z1) * n1 + z1 * hp1;
      hp0 = h0v; hp1 = h1v;
      unsigned long long packed =
          ((unsigned long long)(unsigned)(t + 1) << 32) |
          (unsigned long long)((unsigned)f2bf(h0v) | ((unsigned)f2bf(h1v) << 16));
      __hip_atomic_store(&hout[cb * 980 + (k0 >> 1) + p], packed,
                         __ATOMIC_RELAXED, __HIP_MEMORY_SCOPE_AGENT);
    }
    __syncthreads();  // protect s_h/s_gi/s_gh reuse next iteration
  }
}

// ---------- kernel 6: fc + softmax + labels (tagged-u64 h) ----------
__global__ void k_fc(const unsigned long long* __restrict__ h, const float* __restrict__ fc_w,
                     const float* __restrict__ fc_b, const int* __restrict__ labels,
                     float* __restrict__ out) {
  const int l = threadIdx.x;
  float acc[8];
#pragma unroll
  for (int i = 0; i < 8; ++i) acc[i] = 0.f;
  for (int p = l; p < 980; p += 64) {
    const float w0a = fc_w[2 * p], w0b = fc_w[2 * p + 1];
    const float w1a = fc_w[1960 + 2 * p], w1b = fc_w[1960 + 2 * p + 1];
#pragma unroll
    for (int b = 0; b < 4; ++b) {
      unsigned int d = (unsigned int)h[b * 980 + p];
      float ha = bf2f((unsigned short)(d & 0xffff));
      float hb = bf2f((unsigned short)(d >> 16));
      acc[b * 2 + 0] += ha * w0a + hb * w0b;
      acc[b * 2 + 1] += ha * w1a + hb * w1b;
    }
  }
#pragma unroll
  for (int i = 0; i < 8; ++i) {
    float a = acc[i];
#pragma unroll
    for (int off = 32; off; off >>= 1) a += __shfl_xor(a, off, 64);
    acc[i] = a;
  }
  if (l == 0) {
#pragma unroll
    for (int b = 0; b < 4; ++b) {
      const float l0 = acc[b * 2] + fc_b[0], l1 = acc[b * 2 + 1] + fc_b[1];
      const float m = fmaxf(l0, l1);
      const float e0 = __expf(l0 - m), e1 = __expf(l1 - m);
      const float s = e0 + e1;
      out[b * 2 + 0] = e0 / s;
      out[b * 2 + 1] = e1 / s;
    }
    for (int i = 0; i < 4; ++i) out[8 + i] = (float)labels[i];
  }
}

extern "C" void kernel_launch(void* const* d_in, const int* in_sizes, int n_in,
                              void* d_out, int out_size, void* d_ws, size_t ws_size,
                              hipStream_t stream) {
  const float* x       = (const float*)d_in[0];
  const float* hx0     = (const float*)d_in[1];
  const int*   labels  = (const int*)d_in[2];
  const float* conv1_w = (const float*)d_in[3];
  const float* conv1_b = (const float*)d_in[4];
  const float* conv2_w = (const float*)d_in[5];
  const float* conv2_b = (const float*)d_in[6];
  const float* w_ih    = (const float*)d_in[7];
  const float* w_hh    = (const float*)d_in[8];
  const float* b_ih    = (const float*)d_in[9];
  const float* b_hh    = (const float*)d_in[10];
  const float* fc_w    = (const float*)d_in[11];
  const float* fc_b    = (const float*)d_in[12];

  char* ws = (char*)d_ws;
  size_t off = 0;
  unsigned short* pool1 = (unsigned short*)(ws + off); off += (size_t)128 * 84 * 41 * 64 * 2;  // 56.4MB
  unsigned short* feat_bf = (unsigned short*)(ws + off); off += (size_t)128 * KP * 2;          // 0.5MB
  float* gi    = (float*)(ws + off); off += (size_t)128 * 5880 * 4;                            // 3.0MB
  unsigned short* whh_bf = (unsigned short*)(ws + off); off += (size_t)5880 * 1960 * 2;        // 23.0MB
  unsigned short* wih_bf = (unsigned short*)(ws + off); off += (size_t)NP * KP * 2;            // 23.4MB
  unsigned long long* hb0 = (unsigned long long*)(ws + off); off += (size_t)4 * 980 * 8;       // 31.4KB
  unsigned long long* hb1 = (unsigned long long*)(ws + off); off += (size_t)4 * 980 * 8;       // 31.4KB
  unsigned short* w1f = (unsigned short*)(ws + off); off += (size_t)4 * 4 * 64 * 8 * 2;        // 16KB
  unsigned short* w2f = (unsigned short*)(ws + off); off += (size_t)32 * 64 * 8 * 2;           // 32KB

  k_cvt<<<2048, 256, 0, stream>>>(w_hh, whh_bf, 5880 * 1960 / 4);
  k_cvt_wih<<<(NP * KP / 8 + 255) / 256, 256, 0, stream>>>(w_ih, wih_bf);
  k_w1frag<<<32, 256, 0, stream>>>(conv1_w, w1f);
  k_w2frag<<<64, 256, 0, stream>>>(conv2_w, w2f);
  k_featpad<<<1, 256, 0, stream>>>(feat_bf, hb0, hb1);

  dim3 g1(128, 21);
  k_conv1<<<g1, 256, 0, stream>>>(x, w1f, conv1_b, pool1);

  dim3 g2(128, 14);
  k_conv2<<<g2, 128, 0, stream>>>(pool1, w2f, conv2_b, feat_bf);

  dim3 g3(368, 2);
  k_gi<<<g3, 256, 0, stream>>>(feat_bf, wih_bf, b_ih, gi);

  // all 32 GRU steps, persistent MFMA, data-tagged sync; final h_32 in hb0
  void* gru_args[] = {(void*)&whh_bf, (void*)&b_hh, (void*)&gi, (void*)&hx0,
                      (void*)&hb0, (void*)&hb1};
  hipLaunchCooperativeKernel((const void*)k_gru, dim3(GRU_BLOCKS), dim3(512), gru_args, 0, stream);

  k_fc<<<1, 64, 0, stream>>>(hb0, fc_w, fc_b, labels, (float*)d_out);
}